// Round 7
// baseline (1220.577 us; speedup 1.0000x reference)
//
#include <hip/hip_runtime.h>

#define NPOST 100000
#define NUSER 50000
#define NENT  20000
#define NDTOT 420000
#define ETOT  1550000
#define NSCANBLK 206

typedef short short8 __attribute__((ext_vector_type(8)));
typedef float f32x4 __attribute__((ext_vector_type(4)));
typedef unsigned short ushort4v __attribute__((ext_vector_type(4)));

static __device__ __forceinline__ unsigned short f2bf(float x){
  union { float f; unsigned u; } v; v.f = x;
  unsigned r = v.u + 0x7FFF + ((v.u >> 16) & 1);
  return (unsigned short)(r >> 16);
}
static __device__ __forceinline__ float bf2f(unsigned short h){
  union { unsigned u; float f; } v; v.u = ((unsigned)h) << 16;
  return v.f;
}

struct EdgeMeta {
  const int* src[6];
  const int* dst[6];
  int E[6];
  int degoff[6];
};

// ---------------- fused prep kernel ----------------

static __device__ __forceinline__ void d_split(const float* __restrict__ X,
                                               unsigned short* __restrict__ H,
                                               unsigned short* __restrict__ L, int i){
  float x = X[i];
  unsigned short h = f2bf(x);
  H[i] = h;
  L[i] = f2bf(x - bf2f(h));
}

static __device__ __forceinline__ void d_layerB(const float* __restrict__ Wsrc,
                                                unsigned short* __restrict__ H,
                                                unsigned short* __restrict__ L, int idx){
  const int off[6]  = {0, 24576, 40960, 49152, 73728, 90112};
  const int Ks[6]   = {384, 256, 128, 384, 256, 128};
  int seg = 5;
  #pragma unroll
  for (int s = 4; s >= 0; s--) if (idx < off[s + 1]) seg = s;
  int l = seg / 3, type = seg % 3;
  int K = Ks[seg];
  int rem = idx - off[seg];
  int n = rem / K, k = rem - n * K;
  int slot = k >> 7, head = (k >> 6) & 1, kk = k & 63;
  int rel;
  if (type == 0)      rel = (slot == 0) ? 0 : (slot == 1 ? 1 : 5);
  else if (type == 1) rel = (slot == 0) ? 3 : 4;
  else                rel = 2;
  int m = l * 6 + rel;
  float x = Wsrc[(size_t)m * 8192 + (head * 64 + n) * 64 + kk];
  unsigned short h = f2bf(x);
  H[idx] = h;
  L[idx] = f2bf(x - bf2f(h));
}

static __device__ __forceinline__ void d_weff(const float* __restrict__ W,
                                              const float* __restrict__ a,
                                              float* __restrict__ weff, int idx){
  int m = idx >> 7;
  int rem = idx & 127;
  int h = rem >> 6, k = rem & 63;
  const float* Wm = W + m * 8192;
  const float* am = a + m * 128;
  float acc = 0.f;
  #pragma unroll 8
  for (int c = 0; c < 64; c++)
    acc += Wm[(h * 64 + c) * 64 + k] * am[h * 64 + c];
  weff[idx] = acc;
}

static __device__ __forceinline__ void d_bias(const float* __restrict__ gatb,
                                              float* __restrict__ bsum, int idx){
  int c = idx & 63;
  int lt = idx >> 6;
  int l = lt / 3, t = lt % 3;
  float v;
  if (t == 0)      v = gatb[(l*6+0)*64+c] + gatb[(l*6+1)*64+c] + gatb[(l*6+5)*64+c];
  else if (t == 1) v = gatb[(l*6+3)*64+c] + gatb[(l*6+4)*64+c];
  else             v = gatb[(l*6+2)*64+c];
  bsum[lt * 64 + c] = v;
}

__global__ void k_prep(const float* __restrict__ Wp, const float* __restrict__ Wu,
                       const float* __restrict__ We, const float* __restrict__ Wsrc,
                       const float* __restrict__ Wdst, const float* __restrict__ asrc,
                       const float* __restrict__ adst, const float* __restrict__ gatb,
                       unsigned short* WpH, unsigned short* WpL,
                       unsigned short* WuH, unsigned short* WuL,
                       unsigned short* WeH, unsigned short* WeL,
                       unsigned short* lbH, unsigned short* lbL,
                       float* weff_s, float* weff_d, float* bsum){
  int idx = blockIdx.x * 256 + threadIdx.x;
  if (idx < 49152)       d_split(Wp, WpH, WpL, idx);
  else if (idx < 51200)  d_split(Wu, WuH, WuL, idx - 49152);
  else if (idx < 55296)  d_split(We, WeH, WeL, idx - 51200);
  else if (idx < 153600) d_layerB(Wsrc, lbH, lbL, idx - 55296);
  else if (idx < 155136) d_weff(Wsrc, asrc, weff_s, idx - 153600);
  else if (idx < 156672) d_weff(Wdst, adst, weff_d, idx - 155136);
  else if (idx < 157056) d_bias(gatb, bsum, idx - 156672);
}

// ---------------- CSR build ----------------

__global__ void k_hist(EdgeMeta em, int* __restrict__ deg){
  int r = blockIdx.y;
  int e = blockIdx.x * blockDim.x + threadIdx.x;
  if (e >= em.E[r]) return;
  atomicAdd(&deg[em.degoff[r] + em.dst[r][e]], 1);
}

__global__ __launch_bounds__(256) void k_scanA(const int* __restrict__ deg,
                                               int* __restrict__ rowstart,
                                               int* __restrict__ blocksum){
  __shared__ int sums[256];
  int t = threadIdx.x;
  int base = blockIdx.x * 2048 + t * 8;
  int v[8]; int s = 0;
  #pragma unroll
  for (int i = 0; i < 8; i++){
    int j = base + i;
    v[i] = (j < NDTOT) ? deg[j] : 0;
    s += v[i];
  }
  sums[t] = s;
  __syncthreads();
  for (int off = 1; off < 256; off <<= 1){
    int x = (t >= off) ? sums[t - off] : 0;
    __syncthreads();
    sums[t] += x;
    __syncthreads();
  }
  int excl = (t > 0) ? sums[t - 1] : 0;
  if (t == 255) blocksum[blockIdx.x] = sums[255];
  int run = excl;
  #pragma unroll
  for (int i = 0; i < 8; i++){
    int j = base + i;
    if (j < NDTOT) rowstart[j] = run;
    run += v[i];
  }
}

__global__ __launch_bounds__(256) void k_scanB(int* __restrict__ blocksum){
  __shared__ int s[256];
  int t = threadIdx.x;
  s[t] = (t < NSCANBLK) ? blocksum[t] : 0;
  __syncthreads();
  for (int off = 1; off < 256; off <<= 1){
    int x = (t >= off) ? s[t - off] : 0;
    __syncthreads();
    s[t] += x;
    __syncthreads();
  }
  int excl = (t > 0) ? s[t - 1] : 0;
  if (t < NSCANBLK) blocksum[t] = excl;
}

// scanC also initializes cursor (folds the old D2D memcpy)
__global__ void k_scanC(int* __restrict__ rowstart, const int* __restrict__ blocksum,
                        int* __restrict__ cursor){
  int j = blockIdx.x * blockDim.x + threadIdx.x;
  if (j < NDTOT){
    int v = rowstart[j] + blocksum[j >> 11];
    rowstart[j] = v;
    cursor[j] = v;
  }
  if (j == 0) rowstart[NDTOT] = ETOT;
}

__global__ void k_scatter(EdgeMeta em, int* __restrict__ cursor, int* __restrict__ csr_src){
  int r = blockIdx.y;
  int e = blockIdx.x * blockDim.x + threadIdx.x;
  if (e >= em.E[r]) return;
  int d = em.dst[r][e];
  int pos = atomicAdd(&cursor[em.degoff[r] + d], 1);
  csr_src[pos] = em.src[r][e];
}

// ---------------- fused CSR aggregation -> split bf16 planes ----------------
// 4 rows per wave, 16 lanes per row. Lane covers 4 h-columns via ONE float4
// gather -> one global_load_dwordx4 serves 4 edges (1KB/instr). Divergent
// per-group edge loop (exec-masked), one-edge-ahead pipeline. Per-column
// accumulation order identical to R1 (sequential CSR order, fmaf) ->
// bitwise-identical output.

struct AggArgs {
  const float* h[3];            // cur h per node type (post, user, ent)
  unsigned short* aggH[3];
  unsigned short* aggL[3];
  const float* als;             // als_all base
  const float* ald;             // ald_all base (indexed by global CSR row)
  const int* rowstart;
  const int* csr;
};

__global__ __launch_bounds__(256) void k_agg_all(AggArgs A){
  int wid = (blockIdx.x * blockDim.x + threadIdx.x) >> 6;
  int lane = threadIdx.x & 63;
  int g = lane >> 4, lg = lane & 15;
  int gw = wid * 4 + g;                 // CSR row handled by this 16-lane group
  if (gw >= NDTOT) return;
  int dst0, st, dt, slot, alsoff;
  if (gw < 100000)      { dst0 = gw;          st = 1; dt = 0; slot = 0; alsoff = 0;      }
  else if (gw < 200000) { dst0 = gw - 100000; st = 1; dt = 0; slot = 1; alsoff = 50000;  }
  else if (gw < 220000) { dst0 = gw - 200000; st = 0; dt = 2; slot = 0; alsoff = 100000; }
  else if (gw < 270000) { dst0 = gw - 220000; st = 1; dt = 1; slot = 0; alsoff = 200000; }
  else if (gw < 320000) { dst0 = gw - 270000; st = 1; dt = 1; slot = 1; alsoff = 250000; }
  else                  { dst0 = gw - 320000; st = 0; dt = 0; slot = 2; alsoff = 300000; }
  const float* __restrict__ h = A.h[st];
  const float* __restrict__ als = A.als + (size_t)alsoff * 2;
  float2 ad = *(const float2*)(A.ald + (size_t)gw * 2);
  int rs = A.rowstart[gw];
  int re = A.rowstart[gw + 1];
  float4 a0 = {0.f,0.f,0.f,0.f}, a1 = {0.f,0.f,0.f,0.f};
  float s0 = 0.f, s1 = 0.f;
  if (re > rs){
    // one-edge-ahead pipeline
    int sidx = A.csr[rs];
    float2 as = *(const float2*)(als + (size_t)sidx * 2);
    float4 hv = *(const float4*)(h + (size_t)sidx * 64 + lg * 4);
    for (int e = rs; e < re; e++){
      int nsidx = (e + 1 < re) ? A.csr[e + 1] : sidx;
      float2 nas = *(const float2*)(als + (size_t)nsidx * 2);
      float4 nhv = *(const float4*)(h + (size_t)nsidx * 64 + lg * 4);
      float e0 = as.x + ad.x, e1 = as.y + ad.y;
      e0 = e0 > 0.f ? e0 : 0.2f * e0;
      e1 = e1 > 0.f ? e1 : 0.2f * e1;
      float p0 = __expf(e0), p1 = __expf(e1);
      a0.x = fmaf(p0, hv.x, a0.x); a0.y = fmaf(p0, hv.y, a0.y);
      a0.z = fmaf(p0, hv.z, a0.z); a0.w = fmaf(p0, hv.w, a0.w);
      a1.x = fmaf(p1, hv.x, a1.x); a1.y = fmaf(p1, hv.y, a1.y);
      a1.z = fmaf(p1, hv.z, a1.z); a1.w = fmaf(p1, hv.w, a1.w);
      s0 += p0; s1 += p1;
      as = nas; hv = nhv; sidx = nsidx;
    }
  }
  float r0 = s0 > 0.f ? 0.5f / s0 : 0.f;
  float r1 = s1 > 0.f ? 0.5f / s1 : 0.f;
  float v0x = a0.x*r0, v0y = a0.y*r0, v0z = a0.z*r0, v0w = a0.w*r0;
  float v1x = a1.x*r1, v1y = a1.y*r1, v1z = a1.z*r1, v1w = a1.w*r1;
  int K = (dt == 0) ? 384 : ((dt == 1) ? 256 : 128);
  size_t base2 = (size_t)dst0 * K + slot * 128 + lg * 4;
  unsigned short* __restrict__ aggH = A.aggH[dt];
  unsigned short* __restrict__ aggL = A.aggL[dt];
  ushort4v h0, h1, l0, l1;
  h0[0]=f2bf(v0x); h0[1]=f2bf(v0y); h0[2]=f2bf(v0z); h0[3]=f2bf(v0w);
  h1[0]=f2bf(v1x); h1[1]=f2bf(v1y); h1[2]=f2bf(v1z); h1[3]=f2bf(v1w);
  l0[0]=f2bf(v0x-bf2f(h0[0])); l0[1]=f2bf(v0y-bf2f(h0[1]));
  l0[2]=f2bf(v0z-bf2f(h0[2])); l0[3]=f2bf(v0w-bf2f(h0[3]));
  l1[0]=f2bf(v1x-bf2f(h1[0])); l1[1]=f2bf(v1y-bf2f(h1[1]));
  l1[2]=f2bf(v1z-bf2f(h1[2])); l1[3]=f2bf(v1w-bf2f(h1[3]));
  *(ushort4v*)(aggH + base2)      = h0;
  *(ushort4v*)(aggH + base2 + 64) = h1;
  *(ushort4v*)(aggL + base2)      = l0;
  *(ushort4v*)(aggL + base2 + 64) = l1;
}

// ---------------- MFMA GEMM (3 fused segments) + fused attention-logit epilogue ----------------
// C[N,64] = act(A[N,K] @ Bt^T + bias); then per attention job jb (<=6), compute
// al[row] = (C_row . weff_head0, C_row . weff_head1) via 4 fma partials +
// 16-lane butterfly reduce, writing als/ald for the NEXT stage directly from
// registers (kills the k_al_all kernel and its ~210 MB/layer h re-read).
// LDS XOR swizzle: element (row,k) at row*32 + (((k>>3)^((row>>2)&3))<<3) + (k&7).

static __device__ __forceinline__ int swz(int row, int k){
  return row * 32 + ((((k >> 3) ^ ((row >> 2) & 3))) << 3) + (k & 7);
}

struct GSeg {
  const float* A32;
  const unsigned short* AH;
  const unsigned short* AL;
  const unsigned short* BH;
  const unsigned short* BL;
  const float* bias;
  float* C;
  int N; int K; int blk0;
  int naljobs;
  const float* alw[6];   // weff base per job: head0 at [0..63], head1 at [64..127]
  float* alo[6];         // output base per job (float2 per row)
};
struct GArgs { GSeg s[3]; };

template<int ASRC, int RELU>
__global__ __launch_bounds__(256) void k_mfgemm3(GArgs G){
  __shared__ __align__(16) unsigned short sAh[128 * 32];
  __shared__ __align__(16) unsigned short sAl[128 * 32];
  __shared__ __align__(16) unsigned short sBh[64 * 32];
  __shared__ __align__(16) unsigned short sBl[64 * 32];
  __shared__ float weffL[768];
  int b = blockIdx.x;
  GSeg sg = G.s[0];
  if (b >= G.s[1].blk0) sg = G.s[1];
  if (b >= G.s[2].blk0) sg = G.s[2];
  const int N = sg.N, K = sg.K;
  int t = threadIdx.x;
  int w = t >> 6, lane = t & 63;
  int q = lane >> 4, m15 = lane & 15;
  int r0 = (b - sg.blk0) * 128;
  f32x4 acc[2][4];
  #pragma unroll
  for (int i = 0; i < 2; i++)
    #pragma unroll
    for (int j = 0; j < 4; j++)
      acc[i][j] = (f32x4){0.f, 0.f, 0.f, 0.f};

  // stage weff jobs into LDS (visible after first in-loop __syncthreads)
  for (int i = t; i < sg.naljobs * 128; i += 256)
    weffL[i] = sg.alw[i >> 7][i & 127];

  int arow = t >> 1, akb = (t & 1) * 16;
  int brow = t >> 2, bkb = (t & 3) * 8;

  for (int k0 = 0; k0 < K; k0 += 32){
    // ---- stage A ----
    int gr = r0 + arow;
    if (ASRC == 0){
      float v[16];
      if (gr < N){
        const float4* ap = (const float4*)(sg.A32 + (size_t)gr * K + k0 + akb);
        #pragma unroll
        for (int i = 0; i < 4; i++){
          float4 f = ap[i];
          v[i*4+0] = f.x; v[i*4+1] = f.y; v[i*4+2] = f.z; v[i*4+3] = f.w;
        }
      } else {
        #pragma unroll
        for (int i = 0; i < 16; i++) v[i] = 0.f;
      }
      short8 h0, h1, l0, l1;
      #pragma unroll
      for (int i = 0; i < 8; i++){
        unsigned short hh = f2bf(v[i]);
        h0[i] = (short)hh; l0[i] = (short)f2bf(v[i] - bf2f(hh));
        unsigned short hj = f2bf(v[8+i]);
        h1[i] = (short)hj; l1[i] = (short)f2bf(v[8+i] - bf2f(hj));
      }
      *(short8*)(sAh + swz(arow, akb))     = h0;
      *(short8*)(sAh + swz(arow, akb + 8)) = h1;
      *(short8*)(sAl + swz(arow, akb))     = l0;
      *(short8*)(sAl + swz(arow, akb + 8)) = l1;
    } else {
      short8 h0 = {0,0,0,0,0,0,0,0}, h1 = {0,0,0,0,0,0,0,0};
      short8 l0 = {0,0,0,0,0,0,0,0}, l1 = {0,0,0,0,0,0,0,0};
      if (gr < N){
        const short8* hp = (const short8*)(sg.AH + (size_t)gr * K + k0 + akb);
        const short8* lp = (const short8*)(sg.AL + (size_t)gr * K + k0 + akb);
        h0 = hp[0]; h1 = hp[1];
        l0 = lp[0]; l1 = lp[1];
      }
      *(short8*)(sAh + swz(arow, akb))     = h0;
      *(short8*)(sAh + swz(arow, akb + 8)) = h1;
      *(short8*)(sAl + swz(arow, akb))     = l0;
      *(short8*)(sAl + swz(arow, akb + 8)) = l1;
    }
    // ---- stage B ----
    {
      short8 bh = *(const short8*)(sg.BH + (size_t)brow * K + k0 + bkb);
      short8 bl = *(const short8*)(sg.BL + (size_t)brow * K + k0 + bkb);
      *(short8*)(sBh + swz(brow, bkb)) = bh;
      *(short8*)(sBl + swz(brow, bkb)) = bl;
    }
    __syncthreads();
    // ---- fragments + MFMA ----
    short8 ah[2], al_[2];
    #pragma unroll
    for (int i = 0; i < 2; i++){
      int mrow = w * 32 + i * 16 + m15;
      ah[i]  = *(const short8*)(sAh + swz(mrow, q * 8));
      al_[i] = *(const short8*)(sAl + swz(mrow, q * 8));
    }
    #pragma unroll
    for (int j = 0; j < 4; j++){
      int bn = j * 16 + m15;
      short8 bh = *(const short8*)(sBh + swz(bn, q * 8));
      short8 bl = *(const short8*)(sBl + swz(bn, q * 8));
      #pragma unroll
      for (int i = 0; i < 2; i++){
        acc[i][j] = __builtin_amdgcn_mfma_f32_16x16x32_bf16(ah[i],  bh, acc[i][j], 0, 0, 0);
        acc[i][j] = __builtin_amdgcn_mfma_f32_16x16x32_bf16(ah[i],  bl, acc[i][j], 0, 0, 0);
        acc[i][j] = __builtin_amdgcn_mfma_f32_16x16x32_bf16(al_[i], bh, acc[i][j], 0, 0, 0);
      }
    }
    __syncthreads();
  }
  // ---- epilogue: bias + activation (in place) ----
  #pragma unroll
  for (int j = 0; j < 4; j++){
    float bv = sg.bias[j * 16 + m15];
    #pragma unroll
    for (int i = 0; i < 2; i++){
      #pragma unroll
      for (int r = 0; r < 4; r++){
        float vv = acc[i][j][r] + bv;
        if (RELU) vv = vv > 0.f ? vv : 0.f;
        acc[i][j][r] = vv;
      }
    }
  }
  // ---- store C ----
  #pragma unroll
  for (int j = 0; j < 4; j++){
    int col = j * 16 + m15;
    #pragma unroll
    for (int i = 0; i < 2; i++){
      #pragma unroll
      for (int r = 0; r < 4; r++){
        int row = r0 + w * 32 + i * 16 + q * 4 + r;
        if (row < N) sg.C[(size_t)row * 64 + col] = acc[i][j][r];
      }
    }
  }
  // ---- fused attention logits for next stage ----
  for (int jb = 0; jb < sg.naljobs; jb++){
    const float* wj = weffL + jb * 128;
    #pragma unroll
    for (int i = 0; i < 2; i++){
      #pragma unroll
      for (int r = 0; r < 4; r++){
        float p0 = 0.f, p1 = 0.f;
        #pragma unroll
        for (int j = 0; j < 4; j++){
          float v = acc[i][j][r];
          p0 = fmaf(v, wj[j * 16 + m15], p0);
          p1 = fmaf(v, wj[64 + j * 16 + m15], p1);
        }
        #pragma unroll
        for (int mask = 1; mask < 16; mask <<= 1){
          p0 += __shfl_xor(p0, mask);
          p1 += __shfl_xor(p1, mask);
        }
        int row = r0 + w * 32 + i * 16 + q * 4 + r;
        if (m15 == 0 && row < N){
          float2 o; o.x = p0; o.y = p1;
          *(float2*)(sg.alo[jb] + (size_t)row * 2) = o;
        }
      }
    }
  }
}

// ---------------- classifier head ----------------

__global__ __launch_bounds__(256) void k_classifier(const float* __restrict__ hpost,
                                                    const float* __restrict__ w1,
                                                    const float* __restrict__ b1,
                                                    const float* __restrict__ w2,
                                                    const float* __restrict__ b2,
                                                    float* __restrict__ out, int N){
  __shared__ float w1s[32 * 64];
  __shared__ float b1s[32];
  __shared__ float w2s[32];
  for (int i = threadIdx.x; i < 2048; i += 256) w1s[i] = w1[i];
  if (threadIdx.x < 32){
    b1s[threadIdx.x] = b1[threadIdx.x];
    w2s[threadIdx.x] = w2[threadIdx.x];
  }
  __syncthreads();
  float bias2 = b2[0];
  for (int n = blockIdx.x * blockDim.x + threadIdx.x; n < N; n += gridDim.x * blockDim.x){
    float4 hr[16];
    const float4* hp = (const float4*)(hpost + (size_t)n * 64);
    #pragma unroll
    for (int q = 0; q < 16; q++) hr[q] = hp[q];
    float o = bias2;
    #pragma unroll 4
    for (int j = 0; j < 32; j++){
      float dacc = b1s[j];
      const float4* wr = (const float4*)(w1s + j * 64);
      #pragma unroll
      for (int q = 0; q < 16; q++){
        float4 w = wr[q]; float4 v = hr[q];
        dacc += w.x*v.x + w.y*v.y + w.z*v.z + w.w*v.w;
      }
      dacc = dacc > 0.f ? dacc : 0.f;
      o += w2s[j] * dacc;
    }
    out[n] = o;
  }
}

// ---------------- host ----------------

static inline size_t align256(size_t x){ return (x + 255) & ~(size_t)255; }

extern "C" void kernel_launch(void* const* d_in, const int* in_sizes, int n_in,
                              void* d_out, int out_size, void* d_ws, size_t ws_size,
                              hipStream_t stream){
  (void)in_sizes; (void)n_in; (void)out_size; (void)ws_size;
  const float* x_post = (const float*)d_in[0];
  const float* x_user = (const float*)d_in[1];
  const float* x_ent  = (const float*)d_in[2];
  EdgeMeta em;
  for (int r = 0; r < 6; r++){
    em.src[r] = (const int*)d_in[3 + 2*r];
    em.dst[r] = (const int*)d_in[4 + 2*r];
  }
  const int Earr[6] = {100000, 200000, 200000, 400000, 400000, 250000};
  const int dgo[6]  = {0, 100000, 200000, 220000, 270000, 320000};
  for (int r = 0; r < 6; r++){ em.E[r] = Earr[r]; em.degoff[r] = dgo[r]; }

  const float* Wp   = (const float*)d_in[15]; const float* bp = (const float*)d_in[16];
  const float* Wu   = (const float*)d_in[17]; const float* bu = (const float*)d_in[18];
  const float* We   = (const float*)d_in[19]; const float* be = (const float*)d_in[20];
  const float* Wsrc = (const float*)d_in[21];
  const float* Wdst = (const float*)d_in[22];
  const float* asrc = (const float*)d_in[23];
  const float* adst = (const float*)d_in[24];
  const float* gatb = (const float*)d_in[25];
  const float* cw1  = (const float*)d_in[26]; const float* cb1 = (const float*)d_in[27];
  const float* cw2  = (const float*)d_in[28]; const float* cb2 = (const float*)d_in[29];
  float* out = (float*)d_out;

  const int NN[3] = {NPOST, NUSER, NENT};

  // ---- workspace ----
  char* p = (char*)d_ws;
  auto alloc = [&](size_t bytes){ char* r = p; p += align256(bytes); return r; };
  float* hA[3]; float* hB[3];
  for (int i = 0; i < 3; i++) hA[i] = (float*)alloc((size_t)NN[i] * 64 * 4);
  for (int i = 0; i < 3; i++) hB[i] = (float*)alloc((size_t)NN[i] * 64 * 4);
  float* als_all = (float*)alloc((size_t)400000 * 2 * 4);
  float* ald_all = (float*)alloc((size_t)NDTOT * 2 * 4);
  unsigned short* aggHT[3]; unsigned short* aggLT[3];
  const int KT[3] = {384, 256, 128};
  for (int i = 0; i < 3; i++) aggHT[i] = (unsigned short*)alloc((size_t)NN[i] * KT[i] * 2);
  for (int i = 0; i < 3; i++) aggLT[i] = (unsigned short*)alloc((size_t)NN[i] * KT[i] * 2);
  float* weff_s = (float*)alloc(1536 * 4);
  float* weff_d = (float*)alloc(1536 * 4);
  unsigned short* WpH = (unsigned short*)alloc(768 * 64 * 2);
  unsigned short* WpL = (unsigned short*)alloc(768 * 64 * 2);
  unsigned short* WuH = (unsigned short*)alloc(32 * 64 * 2);
  unsigned short* WuL = (unsigned short*)alloc(32 * 64 * 2);
  unsigned short* WeH = (unsigned short*)alloc(64 * 64 * 2);
  unsigned short* WeL = (unsigned short*)alloc(64 * 64 * 2);
  unsigned short* lbH = (unsigned short*)alloc(98304 * 2);
  unsigned short* lbL = (unsigned short*)alloc(98304 * 2);
  float* bsum   = (float*)alloc(6 * 64 * 4);
  int* deg      = (int*)alloc((size_t)NDTOT * 4);
  int* rowstart = (int*)alloc((size_t)(NDTOT + 1) * 4);
  int* cursor   = (int*)alloc((size_t)NDTOT * 4);
  int* csr_src  = (int*)alloc((size_t)ETOT * 4);
  int* blocksum = (int*)alloc((size_t)NSCANBLK * 4);

  // ---- CSR build (layer-invariant) ----
  hipMemsetAsync(deg, 0, (size_t)NDTOT * 4, stream);
  k_hist<<<dim3(1563, 6), 256, 0, stream>>>(em, deg);
  k_scanA<<<NSCANBLK, 256, 0, stream>>>(deg, rowstart, blocksum);
  k_scanB<<<1, 256, 0, stream>>>(blocksum);
  k_scanC<<<(NDTOT + 255) / 256, 256, 0, stream>>>(rowstart, blocksum, cursor);
  k_scatter<<<dim3(1563, 6), 256, 0, stream>>>(em, cursor, csr_src);

  // ---- weight prep (single fused launch) ----
  k_prep<<<614, 256, 0, stream>>>(Wp, Wu, We, Wsrc, Wdst, asrc, adst, gatb,
                                  WpH, WpL, WuH, WuL, WeH, WeL, lbH, lbL,
                                  weff_s, weff_d, bsum);

  const int BLK0 = 0, BLK1 = (NPOST + 127) / 128, BLK2 = BLK1 + (NUSER + 127) / 128;
  const int BLKT = BLK2 + (NENT + 127) / 128;

  // attention-job tables for layer l (weff m = l*6+r)
  auto setup_aljobs = [&](GSeg& sg, int ty, int l){
    int n = 0;
    auto addS = [&](int r, int base){ sg.alw[n] = weff_s + (l*6+r)*128; sg.alo[n] = als_all + (size_t)base*2; n++; };
    auto addD = [&](int r){ sg.alw[n] = weff_d + (l*6+r)*128; sg.alo[n] = ald_all + (size_t)dgo[r]*2; n++; };
    if (ty == 0){ addS(2, 100000); addS(5, 300000); addD(0); addD(1); addD(5); }
    else if (ty == 1){ addS(0, 0); addS(1, 50000); addS(3, 200000); addS(4, 250000); addD(3); addD(4); }
    else { addD(2); }
    sg.naljobs = n;
    for (int i = n; i < 6; i++){ sg.alw[i] = nullptr; sg.alo[i] = nullptr; }
  };
  auto no_aljobs = [&](GSeg& sg){
    sg.naljobs = 0;
    for (int i = 0; i < 6; i++){ sg.alw[i] = nullptr; sg.alo[i] = nullptr; }
  };

  // ---- input projections (one fused MFMA launch) + layer-0 attention logits ----
  {
    GArgs gp;
    gp.s[0] = { x_post, nullptr, nullptr, WpH, WpL, bp, hA[0], NPOST, 768, BLK0 };
    gp.s[1] = { x_user, nullptr, nullptr, WuH, WuL, bu, hA[1], NUSER,  32, BLK1 };
    gp.s[2] = { x_ent,  nullptr, nullptr, WeH, WeL, be, hA[2], NENT,   64, BLK2 };
    for (int ty = 0; ty < 3; ty++) setup_aljobs(gp.s[ty], ty, 0);
    k_mfgemm3<0, 0><<<BLKT, 256, 0, stream>>>(gp);
  }

  const int segoff[6] = {0, 24576, 40960, 49152, 73728, 90112};  // (l,type) B offsets

  float* cur[3] = {hA[0], hA[1], hA[2]};
  float* nxt[3] = {hB[0], hB[1], hB[2]};

  // agg grid: 105000 waves (4 rows each)
  const int AGG_BLOCKS = ((NDTOT + 3) / 4 * 64) / 256;

  for (int l = 0; l < 2; l++){
    {
      AggArgs aa;
      aa.h[0] = cur[0]; aa.h[1] = cur[1]; aa.h[2] = cur[2];
      for (int i = 0; i < 3; i++){ aa.aggH[i] = aggHT[i]; aa.aggL[i] = aggLT[i]; }
      aa.als = als_all; aa.ald = ald_all;
      aa.rowstart = rowstart; aa.csr = csr_src;
      k_agg_all<<<AGG_BLOCKS, 256, 0, stream>>>(aa);
    }
    {
      GArgs ga;
      ga.s[0] = { nullptr, aggHT[0], aggLT[0], lbH + segoff[l*3+0], lbL + segoff[l*3+0],
                  bsum + (l*3+0)*64, nxt[0], NPOST, 384, BLK0 };
      ga.s[1] = { nullptr, aggHT[1], aggLT[1], lbH + segoff[l*3+1], lbL + segoff[l*3+1],
                  bsum + (l*3+1)*64, nxt[1], NUSER, 256, BLK1 };
      ga.s[2] = { nullptr, aggHT[2], aggLT[2], lbH + segoff[l*3+2], lbL + segoff[l*3+2],
                  bsum + (l*3+2)*64, nxt[2], NENT, 128, BLK2 };
      if (l == 0){ for (int ty = 0; ty < 3; ty++) setup_aljobs(ga.s[ty], ty, 1); }
      else       { for (int ty = 0; ty < 3; ty++) no_aljobs(ga.s[ty]); }
      k_mfgemm3<1, 1><<<BLKT, 256, 0, stream>>>(ga);
    }
    for (int i = 0; i < 3; i++){ float* tmp = cur[i]; cur[i] = nxt[i]; nxt[i] = tmp; }
  }

  k_classifier<<<(NPOST + 255) / 256, 256, 0, stream>>>(cur[0], cw1, cb1, cw2, cb2, out, NPOST);
}

// Round 8
// 1148.837 us; speedup vs baseline: 1.0624x; 1.0624x over previous
//
#include <hip/hip_runtime.h>

#define NPOST 100000
#define NUSER 50000
#define NENT  20000
#define NDTOT 420000
#define ETOT  1550000
#define NSCANBLK 206

typedef short short8 __attribute__((ext_vector_type(8)));
typedef float f32x4 __attribute__((ext_vector_type(4)));
typedef unsigned short ushort4v __attribute__((ext_vector_type(4)));

static __device__ __forceinline__ unsigned short f2bf(float x){
  union { float f; unsigned u; } v; v.f = x;
  unsigned r = v.u + 0x7FFF + ((v.u >> 16) & 1);
  return (unsigned short)(r >> 16);
}
static __device__ __forceinline__ float bf2f(unsigned short h){
  union { unsigned u; float f; } v; v.u = ((unsigned)h) << 16;
  return v.f;
}

struct EdgeMeta {
  const int* src[6];
  const int* dst[6];
  int E[6];
  int degoff[6];
};

// ---------------- fused prep kernel ----------------

static __device__ __forceinline__ void d_split(const float* __restrict__ X,
                                               unsigned short* __restrict__ H,
                                               unsigned short* __restrict__ L, int i){
  float x = X[i];
  unsigned short h = f2bf(x);
  H[i] = h;
  L[i] = f2bf(x - bf2f(h));
}

static __device__ __forceinline__ void d_layerB(const float* __restrict__ Wsrc,
                                                unsigned short* __restrict__ H,
                                                unsigned short* __restrict__ L, int idx){
  const int off[6]  = {0, 24576, 40960, 49152, 73728, 90112};
  const int Ks[6]   = {384, 256, 128, 384, 256, 128};
  int seg = 5;
  #pragma unroll
  for (int s = 4; s >= 0; s--) if (idx < off[s + 1]) seg = s;
  int l = seg / 3, type = seg % 3;
  int K = Ks[seg];
  int rem = idx - off[seg];
  int n = rem / K, k = rem - n * K;
  int slot = k >> 7, head = (k >> 6) & 1, kk = k & 63;
  int rel;
  if (type == 0)      rel = (slot == 0) ? 0 : (slot == 1 ? 1 : 5);
  else if (type == 1) rel = (slot == 0) ? 3 : 4;
  else                rel = 2;
  int m = l * 6 + rel;
  float x = Wsrc[(size_t)m * 8192 + (head * 64 + n) * 64 + kk];
  unsigned short h = f2bf(x);
  H[idx] = h;
  L[idx] = f2bf(x - bf2f(h));
}

static __device__ __forceinline__ void d_weff(const float* __restrict__ W,
                                              const float* __restrict__ a,
                                              float* __restrict__ weff, int idx){
  int m = idx >> 7;
  int rem = idx & 127;
  int h = rem >> 6, k = rem & 63;
  const float* Wm = W + m * 8192;
  const float* am = a + m * 128;
  float acc = 0.f;
  #pragma unroll 8
  for (int c = 0; c < 64; c++)
    acc += Wm[(h * 64 + c) * 64 + k] * am[h * 64 + c];
  weff[idx] = acc;
}

static __device__ __forceinline__ void d_bias(const float* __restrict__ gatb,
                                              float* __restrict__ bsum, int idx){
  int c = idx & 63;
  int lt = idx >> 6;
  int l = lt / 3, t = lt % 3;
  float v;
  if (t == 0)      v = gatb[(l*6+0)*64+c] + gatb[(l*6+1)*64+c] + gatb[(l*6+5)*64+c];
  else if (t == 1) v = gatb[(l*6+3)*64+c] + gatb[(l*6+4)*64+c];
  else             v = gatb[(l*6+2)*64+c];
  bsum[lt * 64 + c] = v;
}

__global__ void k_prep(const float* __restrict__ Wp, const float* __restrict__ Wu,
                       const float* __restrict__ We, const float* __restrict__ Wsrc,
                       const float* __restrict__ Wdst, const float* __restrict__ asrc,
                       const float* __restrict__ adst, const float* __restrict__ gatb,
                       unsigned short* WpH, unsigned short* WpL,
                       unsigned short* WuH, unsigned short* WuL,
                       unsigned short* WeH, unsigned short* WeL,
                       unsigned short* lbH, unsigned short* lbL,
                       float* weff_s, float* weff_d, float* bsum){
  int idx = blockIdx.x * 256 + threadIdx.x;
  if (idx < 49152)       d_split(Wp, WpH, WpL, idx);
  else if (idx < 51200)  d_split(Wu, WuH, WuL, idx - 49152);
  else if (idx < 55296)  d_split(We, WeH, WeL, idx - 51200);
  else if (idx < 153600) d_layerB(Wsrc, lbH, lbL, idx - 55296);
  else if (idx < 155136) d_weff(Wsrc, asrc, weff_s, idx - 153600);
  else if (idx < 156672) d_weff(Wdst, adst, weff_d, idx - 155136);
  else if (idx < 157056) d_bias(gatb, bsum, idx - 156672);
}

// ---------------- CSR build ----------------

__global__ void k_hist(EdgeMeta em, int* __restrict__ deg){
  int r = blockIdx.y;
  int e = blockIdx.x * blockDim.x + threadIdx.x;
  if (e >= em.E[r]) return;
  atomicAdd(&deg[em.degoff[r] + em.dst[r][e]], 1);
}

__global__ __launch_bounds__(256) void k_scanA(const int* __restrict__ deg,
                                               int* __restrict__ rowstart,
                                               int* __restrict__ blocksum){
  __shared__ int sums[256];
  int t = threadIdx.x;
  int base = blockIdx.x * 2048 + t * 8;
  int v[8]; int s = 0;
  #pragma unroll
  for (int i = 0; i < 8; i++){
    int j = base + i;
    v[i] = (j < NDTOT) ? deg[j] : 0;
    s += v[i];
  }
  sums[t] = s;
  __syncthreads();
  for (int off = 1; off < 256; off <<= 1){
    int x = (t >= off) ? sums[t - off] : 0;
    __syncthreads();
    sums[t] += x;
    __syncthreads();
  }
  int excl = (t > 0) ? sums[t - 1] : 0;
  if (t == 255) blocksum[blockIdx.x] = sums[255];
  int run = excl;
  #pragma unroll
  for (int i = 0; i < 8; i++){
    int j = base + i;
    if (j < NDTOT) rowstart[j] = run;
    run += v[i];
  }
}

__global__ __launch_bounds__(256) void k_scanB(int* __restrict__ blocksum){
  __shared__ int s[256];
  int t = threadIdx.x;
  s[t] = (t < NSCANBLK) ? blocksum[t] : 0;
  __syncthreads();
  for (int off = 1; off < 256; off <<= 1){
    int x = (t >= off) ? s[t - off] : 0;
    __syncthreads();
    s[t] += x;
    __syncthreads();
  }
  int excl = (t > 0) ? s[t - 1] : 0;
  if (t < NSCANBLK) blocksum[t] = excl;
}

// scanC also initializes cursor (folds the old D2D memcpy)
__global__ void k_scanC(int* __restrict__ rowstart, const int* __restrict__ blocksum,
                        int* __restrict__ cursor){
  int j = blockIdx.x * blockDim.x + threadIdx.x;
  if (j < NDTOT){
    int v = rowstart[j] + blocksum[j >> 11];
    rowstart[j] = v;
    cursor[j] = v;
  }
  if (j == 0) rowstart[NDTOT] = ETOT;
}

__global__ void k_scatter(EdgeMeta em, int* __restrict__ cursor, int* __restrict__ csr_src){
  int r = blockIdx.y;
  int e = blockIdx.x * blockDim.x + threadIdx.x;
  if (e >= em.E[r]) return;
  int d = em.dst[r][e];
  int pos = atomicAdd(&cursor[em.degoff[r] + d], 1);
  csr_src[pos] = em.src[r][e];
}

// ---------------- fused attention logits ----------------
// src-side jobs: 400000 rows laid out [pub:50k user][rep:50k user][con:100k post]
//                                     [int:50k user][fol:50k user][sim:100k post]
// dst-side jobs: 420000 rows in global CSR row order (degoff layout)

__global__ void k_al_all(const float* __restrict__ h_post, const float* __restrict__ h_user,
                         const float* __restrict__ h_ent,
                         const float* __restrict__ weff_s, const float* __restrict__ weff_d,
                         float* __restrict__ als_all, float* __restrict__ ald_all, int l){
  int idx = blockIdx.x * blockDim.x + threadIdx.x;
  if (idx >= 820000) return;
  const float* h; const float* w; float* out; int node;
  if (idx < 400000){
    int r;
    if (idx < 50000)       { r = 0; node = idx;          h = h_user; }
    else if (idx < 100000) { r = 1; node = idx - 50000;  h = h_user; }
    else if (idx < 200000) { r = 2; node = idx - 100000; h = h_post; }
    else if (idx < 250000) { r = 3; node = idx - 200000; h = h_user; }
    else if (idx < 300000) { r = 4; node = idx - 250000; h = h_user; }
    else                   { r = 5; node = idx - 300000; h = h_post; }
    w = weff_s + (l * 6 + r) * 128;
    out = als_all + (size_t)idx * 2;
  } else {
    int j = idx - 400000;
    int r;
    if (j < 100000)        { r = 0; node = j;          h = h_post; }
    else if (j < 200000)   { r = 1; node = j - 100000; h = h_post; }
    else if (j < 220000)   { r = 2; node = j - 200000; h = h_ent;  }
    else if (j < 270000)   { r = 3; node = j - 220000; h = h_user; }
    else if (j < 320000)   { r = 4; node = j - 270000; h = h_user; }
    else                   { r = 5; node = j - 320000; h = h_post; }
    w = weff_d + (l * 6 + r) * 128;
    out = ald_all + (size_t)j * 2;
  }
  const float4* hr = (const float4*)(h + (size_t)node * 64);
  const float4* w0 = (const float4*)w;
  const float4* w1 = (const float4*)(w + 64);
  float a0 = 0.f, a1 = 0.f;
  #pragma unroll
  for (int q = 0; q < 16; q++){
    float4 v = hr[q];
    float4 x0 = w0[q], x1 = w1[q];
    a0 += v.x*x0.x + v.y*x0.y + v.z*x0.z + v.w*x0.w;
    a1 += v.x*x1.x + v.y*x1.y + v.z*x1.z + v.w*x1.w;
  }
  out[0] = a0;
  out[1] = a1;
}

// ---------------- fused CSR aggregation -> split bf16 planes ----------------
// 4 rows per wave, 16 lanes per row. Lane covers 4 h-columns via ONE float4
// gather -> one global_load_dwordx4 serves 4 edges (1KB/instr). Divergent
// per-group edge loop (exec-masked), one-edge-ahead pipeline. Per-column
// accumulation order identical to R1 (sequential CSR order, fmaf) ->
// bitwise-identical output.

struct AggArgs {
  const float* h[3];            // cur h per node type (post, user, ent)
  unsigned short* aggH[3];
  unsigned short* aggL[3];
  const float* als;             // als_all base
  const float* ald;             // ald_all base (indexed by global CSR row)
  const int* rowstart;
  const int* csr;
};

__global__ __launch_bounds__(256) void k_agg_all(AggArgs A){
  int wid = (blockIdx.x * blockDim.x + threadIdx.x) >> 6;
  int lane = threadIdx.x & 63;
  int g = lane >> 4, lg = lane & 15;
  int gw = wid * 4 + g;                 // CSR row handled by this 16-lane group
  if (gw >= NDTOT) return;
  int dst0, st, dt, slot, alsoff;
  if (gw < 100000)      { dst0 = gw;          st = 1; dt = 0; slot = 0; alsoff = 0;      }
  else if (gw < 200000) { dst0 = gw - 100000; st = 1; dt = 0; slot = 1; alsoff = 50000;  }
  else if (gw < 220000) { dst0 = gw - 200000; st = 0; dt = 2; slot = 0; alsoff = 100000; }
  else if (gw < 270000) { dst0 = gw - 220000; st = 1; dt = 1; slot = 0; alsoff = 200000; }
  else if (gw < 320000) { dst0 = gw - 270000; st = 1; dt = 1; slot = 1; alsoff = 250000; }
  else                  { dst0 = gw - 320000; st = 0; dt = 0; slot = 2; alsoff = 300000; }
  const float* __restrict__ h = A.h[st];
  const float* __restrict__ als = A.als + (size_t)alsoff * 2;
  float2 ad = *(const float2*)(A.ald + (size_t)gw * 2);
  int rs = A.rowstart[gw];
  int re = A.rowstart[gw + 1];
  float4 a0 = {0.f,0.f,0.f,0.f}, a1 = {0.f,0.f,0.f,0.f};
  float s0 = 0.f, s1 = 0.f;
  if (re > rs){
    // one-edge-ahead pipeline
    int sidx = A.csr[rs];
    float2 as = *(const float2*)(als + (size_t)sidx * 2);
    float4 hv = *(const float4*)(h + (size_t)sidx * 64 + lg * 4);
    for (int e = rs; e < re; e++){
      int nsidx = (e + 1 < re) ? A.csr[e + 1] : sidx;
      float2 nas = *(const float2*)(als + (size_t)nsidx * 2);
      float4 nhv = *(const float4*)(h + (size_t)nsidx * 64 + lg * 4);
      float e0 = as.x + ad.x, e1 = as.y + ad.y;
      e0 = e0 > 0.f ? e0 : 0.2f * e0;
      e1 = e1 > 0.f ? e1 : 0.2f * e1;
      float p0 = __expf(e0), p1 = __expf(e1);
      a0.x = fmaf(p0, hv.x, a0.x); a0.y = fmaf(p0, hv.y, a0.y);
      a0.z = fmaf(p0, hv.z, a0.z); a0.w = fmaf(p0, hv.w, a0.w);
      a1.x = fmaf(p1, hv.x, a1.x); a1.y = fmaf(p1, hv.y, a1.y);
      a1.z = fmaf(p1, hv.z, a1.z); a1.w = fmaf(p1, hv.w, a1.w);
      s0 += p0; s1 += p1;
      as = nas; hv = nhv; sidx = nsidx;
    }
  }
  float r0 = s0 > 0.f ? 0.5f / s0 : 0.f;
  float r1 = s1 > 0.f ? 0.5f / s1 : 0.f;
  float v0x = a0.x*r0, v0y = a0.y*r0, v0z = a0.z*r0, v0w = a0.w*r0;
  float v1x = a1.x*r1, v1y = a1.y*r1, v1z = a1.z*r1, v1w = a1.w*r1;
  int K = (dt == 0) ? 384 : ((dt == 1) ? 256 : 128);
  size_t base2 = (size_t)dst0 * K + slot * 128 + lg * 4;
  unsigned short* __restrict__ aggH = A.aggH[dt];
  unsigned short* __restrict__ aggL = A.aggL[dt];
  ushort4v h0, h1, l0, l1;
  h0[0]=f2bf(v0x); h0[1]=f2bf(v0y); h0[2]=f2bf(v0z); h0[3]=f2bf(v0w);
  h1[0]=f2bf(v1x); h1[1]=f2bf(v1y); h1[2]=f2bf(v1z); h1[3]=f2bf(v1w);
  l0[0]=f2bf(v0x-bf2f(h0[0])); l0[1]=f2bf(v0y-bf2f(h0[1]));
  l0[2]=f2bf(v0z-bf2f(h0[2])); l0[3]=f2bf(v0w-bf2f(h0[3]));
  l1[0]=f2bf(v1x-bf2f(h1[0])); l1[1]=f2bf(v1y-bf2f(h1[1]));
  l1[2]=f2bf(v1z-bf2f(h1[2])); l1[3]=f2bf(v1w-bf2f(h1[3]));
  *(ushort4v*)(aggH + base2)      = h0;
  *(ushort4v*)(aggH + base2 + 64) = h1;
  *(ushort4v*)(aggL + base2)      = l0;
  *(ushort4v*)(aggL + base2 + 64) = l1;
}

// ---------------- MFMA GEMM (3 fused segments): C[N,64] = act(A[N,K] @ Bt^T + bias) ----------------
// Tile 128 rows x 64 cols, K-chunk 32, 4 waves; 16x16x32 bf16 MFMA, 3-MFMA split product.
// Register double-buffered staging (T14): next K-chunk's global loads are issued
// before the current chunk's LDS-store + MFMA, hiding global latency under the
// compute phase. Plain VGPR loads legally stay in flight across __syncthreads.
// LDS XOR swizzle: element (row,k) at row*32 + (((k>>3)^((row>>2)&3))<<3) + (k&7).

static __device__ __forceinline__ int swz(int row, int k){
  return row * 32 + ((((k >> 3) ^ ((row >> 2) & 3))) << 3) + (k & 7);
}

struct GSeg {
  const float* A32;
  const unsigned short* AH;
  const unsigned short* AL;
  const unsigned short* BH;
  const unsigned short* BL;
  const float* bias;
  float* C;
  int N; int K; int blk0;
};
struct GArgs { GSeg s[3]; };

template<int ASRC, int RELU>
__global__ __launch_bounds__(256) void k_mfgemm3(GArgs G){
  __shared__ __align__(16) unsigned short sAh[128 * 32];
  __shared__ __align__(16) unsigned short sAl[128 * 32];
  __shared__ __align__(16) unsigned short sBh[64 * 32];
  __shared__ __align__(16) unsigned short sBl[64 * 32];
  int b = blockIdx.x;
  GSeg sg = G.s[0];
  if (b >= G.s[1].blk0) sg = G.s[1];
  if (b >= G.s[2].blk0) sg = G.s[2];
  const int N = sg.N, K = sg.K;
  int t = threadIdx.x;
  int w = t >> 6, lane = t & 63;
  int q = lane >> 4, m15 = lane & 15;
  int r0 = (b - sg.blk0) * 128;
  f32x4 acc[2][4];
  #pragma unroll
  for (int i = 0; i < 2; i++)
    #pragma unroll
    for (int j = 0; j < 4; j++)
      acc[i][j] = (f32x4){0.f, 0.f, 0.f, 0.f};

  int arow = t >> 1, akb = (t & 1) * 16;
  int brow = t >> 2, bkb = (t & 3) * 8;
  int gr = r0 + arow;
  bool avalid = gr < N;

  // ---- current-chunk registers (chunk 0 loaded in prologue) ----
  float4 fA0 = {0,0,0,0}, fA1 = {0,0,0,0}, fA2 = {0,0,0,0}, fA3 = {0,0,0,0};
  short8 hA0 = {0,0,0,0,0,0,0,0}, hA1 = {0,0,0,0,0,0,0,0};
  short8 lA0 = {0,0,0,0,0,0,0,0}, lA1 = {0,0,0,0,0,0,0,0};
  short8 bH, bL;
  if (ASRC == 0){
    if (avalid){
      const float4* ap = (const float4*)(sg.A32 + (size_t)gr * K + akb);
      fA0 = ap[0]; fA1 = ap[1]; fA2 = ap[2]; fA3 = ap[3];
    }
  } else {
    if (avalid){
      const short8* hp = (const short8*)(sg.AH + (size_t)gr * K + akb);
      const short8* lp = (const short8*)(sg.AL + (size_t)gr * K + akb);
      hA0 = hp[0]; hA1 = hp[1]; lA0 = lp[0]; lA1 = lp[1];
    }
  }
  bH = *(const short8*)(sg.BH + (size_t)brow * K + bkb);
  bL = *(const short8*)(sg.BL + (size_t)brow * K + bkb);

  for (int k0 = 0; k0 < K; k0 += 32){
    // ---- issue next-chunk loads early (latency hides under store+MFMA) ----
    float4 fN0 = {0,0,0,0}, fN1 = {0,0,0,0}, fN2 = {0,0,0,0}, fN3 = {0,0,0,0};
    short8 hN0 = {0,0,0,0,0,0,0,0}, hN1 = {0,0,0,0,0,0,0,0};
    short8 lN0 = {0,0,0,0,0,0,0,0}, lN1 = {0,0,0,0,0,0,0,0};
    short8 bHN = {0,0,0,0,0,0,0,0}, bLN = {0,0,0,0,0,0,0,0};
    int k1 = k0 + 32;
    if (k1 < K){
      if (ASRC == 0){
        if (avalid){
          const float4* ap = (const float4*)(sg.A32 + (size_t)gr * K + k1 + akb);
          fN0 = ap[0]; fN1 = ap[1]; fN2 = ap[2]; fN3 = ap[3];
        }
      } else {
        if (avalid){
          const short8* hp = (const short8*)(sg.AH + (size_t)gr * K + k1 + akb);
          const short8* lp = (const short8*)(sg.AL + (size_t)gr * K + k1 + akb);
          hN0 = hp[0]; hN1 = hp[1]; lN0 = lp[0]; lN1 = lp[1];
        }
      }
      bHN = *(const short8*)(sg.BH + (size_t)brow * K + k1 + bkb);
      bLN = *(const short8*)(sg.BL + (size_t)brow * K + k1 + bkb);
    }
    // ---- stage current chunk to LDS ----
    if (ASRC == 0){
      float v[16];
      v[0]=fA0.x; v[1]=fA0.y; v[2]=fA0.z; v[3]=fA0.w;
      v[4]=fA1.x; v[5]=fA1.y; v[6]=fA1.z; v[7]=fA1.w;
      v[8]=fA2.x; v[9]=fA2.y; v[10]=fA2.z; v[11]=fA2.w;
      v[12]=fA3.x; v[13]=fA3.y; v[14]=fA3.z; v[15]=fA3.w;
      short8 h0, h1, l0, l1;
      #pragma unroll
      for (int i = 0; i < 8; i++){
        unsigned short hh = f2bf(v[i]);
        h0[i] = (short)hh; l0[i] = (short)f2bf(v[i] - bf2f(hh));
        unsigned short hj = f2bf(v[8+i]);
        h1[i] = (short)hj; l1[i] = (short)f2bf(v[8+i] - bf2f(hj));
      }
      *(short8*)(sAh + swz(arow, akb))     = h0;
      *(short8*)(sAh + swz(arow, akb + 8)) = h1;
      *(short8*)(sAl + swz(arow, akb))     = l0;
      *(short8*)(sAl + swz(arow, akb + 8)) = l1;
    } else {
      *(short8*)(sAh + swz(arow, akb))     = hA0;
      *(short8*)(sAh + swz(arow, akb + 8)) = hA1;
      *(short8*)(sAl + swz(arow, akb))     = lA0;
      *(short8*)(sAl + swz(arow, akb + 8)) = lA1;
    }
    *(short8*)(sBh + swz(brow, bkb)) = bH;
    *(short8*)(sBl + swz(brow, bkb)) = bL;
    __syncthreads();
    // ---- fragments + MFMA ----
    short8 ah[2], al_[2];
    #pragma unroll
    for (int i = 0; i < 2; i++){
      int mrow = w * 32 + i * 16 + m15;
      ah[i]  = *(const short8*)(sAh + swz(mrow, q * 8));
      al_[i] = *(const short8*)(sAl + swz(mrow, q * 8));
    }
    #pragma unroll
    for (int j = 0; j < 4; j++){
      int bn = j * 16 + m15;
      short8 bh = *(const short8*)(sBh + swz(bn, q * 8));
      short8 bl = *(const short8*)(sBl + swz(bn, q * 8));
      #pragma unroll
      for (int i = 0; i < 2; i++){
        acc[i][j] = __builtin_amdgcn_mfma_f32_16x16x32_bf16(ah[i],  bh, acc[i][j], 0, 0, 0);
        acc[i][j] = __builtin_amdgcn_mfma_f32_16x16x32_bf16(ah[i],  bl, acc[i][j], 0, 0, 0);
        acc[i][j] = __builtin_amdgcn_mfma_f32_16x16x32_bf16(al_[i], bh, acc[i][j], 0, 0, 0);
      }
    }
    __syncthreads();
    // ---- rotate next -> current ----
    fA0 = fN0; fA1 = fN1; fA2 = fN2; fA3 = fN3;
    hA0 = hN0; hA1 = hN1; lA0 = lN0; lA1 = lN1;
    bH = bHN; bL = bLN;
  }
  // ---- epilogue ----
  #pragma unroll
  for (int j = 0; j < 4; j++){
    int col = j * 16 + m15;
    float bv = sg.bias[col];
    #pragma unroll
    for (int i = 0; i < 2; i++){
      #pragma unroll
      for (int r = 0; r < 4; r++){
        int row = r0 + w * 32 + i * 16 + q * 4 + r;
        if (row < N){
          float vv = acc[i][j][r] + bv;
          if (RELU) vv = vv > 0.f ? vv : 0.f;
          sg.C[(size_t)row * 64 + col] = vv;
        }
      }
    }
  }
}

// ---------------- classifier head ----------------

__global__ __launch_bounds__(256) void k_classifier(const float* __restrict__ hpost,
                                                    const float* __restrict__ w1,
                                                    const float* __restrict__ b1,
                                                    const float* __restrict__ w2,
                                                    const float* __restrict__ b2,
                                                    float* __restrict__ out, int N){
  __shared__ float w1s[32 * 64];
  __shared__ float b1s[32];
  __shared__ float w2s[32];
  for (int i = threadIdx.x; i < 2048; i += 256) w1s[i] = w1[i];
  if (threadIdx.x < 32){
    b1s[threadIdx.x] = b1[threadIdx.x];
    w2s[threadIdx.x] = w2[threadIdx.x];
  }
  __syncthreads();
  float bias2 = b2[0];
  for (int n = blockIdx.x * blockDim.x + threadIdx.x; n < N; n += gridDim.x * blockDim.x){
    float4 hr[16];
    const float4* hp = (const float4*)(hpost + (size_t)n * 64);
    #pragma unroll
    for (int q = 0; q < 16; q++) hr[q] = hp[q];
    float o = bias2;
    #pragma unroll 4
    for (int j = 0; j < 32; j++){
      float dacc = b1s[j];
      const float4* wr = (const float4*)(w1s + j * 64);
      #pragma unroll
      for (int q = 0; q < 16; q++){
        float4 w = wr[q]; float4 v = hr[q];
        dacc += w.x*v.x + w.y*v.y + w.z*v.z + w.w*v.w;
      }
      dacc = dacc > 0.f ? dacc : 0.f;
      o += w2s[j] * dacc;
    }
    out[n] = o;
  }
}

// ---------------- host ----------------

static inline size_t align256(size_t x){ return (x + 255) & ~(size_t)255; }

extern "C" void kernel_launch(void* const* d_in, const int* in_sizes, int n_in,
                              void* d_out, int out_size, void* d_ws, size_t ws_size,
                              hipStream_t stream){
  (void)in_sizes; (void)n_in; (void)out_size; (void)ws_size;
  const float* x_post = (const float*)d_in[0];
  const float* x_user = (const float*)d_in[1];
  const float* x_ent  = (const float*)d_in[2];
  EdgeMeta em;
  for (int r = 0; r < 6; r++){
    em.src[r] = (const int*)d_in[3 + 2*r];
    em.dst[r] = (const int*)d_in[4 + 2*r];
  }
  const int Earr[6] = {100000, 200000, 200000, 400000, 400000, 250000};
  const int dgo[6]  = {0, 100000, 200000, 220000, 270000, 320000};
  for (int r = 0; r < 6; r++){ em.E[r] = Earr[r]; em.degoff[r] = dgo[r]; }

  const float* Wp   = (const float*)d_in[15]; const float* bp = (const float*)d_in[16];
  const float* Wu   = (const float*)d_in[17]; const float* bu = (const float*)d_in[18];
  const float* We   = (const float*)d_in[19]; const float* be = (const float*)d_in[20];
  const float* Wsrc = (const float*)d_in[21];
  const float* Wdst = (const float*)d_in[22];
  const float* asrc = (const float*)d_in[23];
  const float* adst = (const float*)d_in[24];
  const float* gatb = (const float*)d_in[25];
  const float* cw1  = (const float*)d_in[26]; const float* cb1 = (const float*)d_in[27];
  const float* cw2  = (const float*)d_in[28]; const float* cb2 = (const float*)d_in[29];
  float* out = (float*)d_out;

  const int NN[3] = {NPOST, NUSER, NENT};

  // ---- workspace ----
  char* p = (char*)d_ws;
  auto alloc = [&](size_t bytes){ char* r = p; p += align256(bytes); return r; };
  float* hA[3]; float* hB[3];
  for (int i = 0; i < 3; i++) hA[i] = (float*)alloc((size_t)NN[i] * 64 * 4);
  for (int i = 0; i < 3; i++) hB[i] = (float*)alloc((size_t)NN[i] * 64 * 4);
  float* als_all = (float*)alloc((size_t)400000 * 2 * 4);
  float* ald_all = (float*)alloc((size_t)NDTOT * 2 * 4);
  unsigned short* aggHT[3]; unsigned short* aggLT[3];
  const int KT[3] = {384, 256, 128};
  for (int i = 0; i < 3; i++) aggHT[i] = (unsigned short*)alloc((size_t)NN[i] * KT[i] * 2);
  for (int i = 0; i < 3; i++) aggLT[i] = (unsigned short*)alloc((size_t)NN[i] * KT[i] * 2);
  float* weff_s = (float*)alloc(1536 * 4);
  float* weff_d = (float*)alloc(1536 * 4);
  unsigned short* WpH = (unsigned short*)alloc(768 * 64 * 2);
  unsigned short* WpL = (unsigned short*)alloc(768 * 64 * 2);
  unsigned short* WuH = (unsigned short*)alloc(32 * 64 * 2);
  unsigned short* WuL = (unsigned short*)alloc(32 * 64 * 2);
  unsigned short* WeH = (unsigned short*)alloc(64 * 64 * 2);
  unsigned short* WeL = (unsigned short*)alloc(64 * 64 * 2);
  unsigned short* lbH = (unsigned short*)alloc(98304 * 2);
  unsigned short* lbL = (unsigned short*)alloc(98304 * 2);
  float* bsum   = (float*)alloc(6 * 64 * 4);
  int* deg      = (int*)alloc((size_t)NDTOT * 4);
  int* rowstart = (int*)alloc((size_t)(NDTOT + 1) * 4);
  int* cursor   = (int*)alloc((size_t)NDTOT * 4);
  int* csr_src  = (int*)alloc((size_t)ETOT * 4);
  int* blocksum = (int*)alloc((size_t)NSCANBLK * 4);

  // ---- CSR build (layer-invariant) ----
  hipMemsetAsync(deg, 0, (size_t)NDTOT * 4, stream);
  k_hist<<<dim3(1563, 6), 256, 0, stream>>>(em, deg);
  k_scanA<<<NSCANBLK, 256, 0, stream>>>(deg, rowstart, blocksum);
  k_scanB<<<1, 256, 0, stream>>>(blocksum);
  k_scanC<<<(NDTOT + 255) / 256, 256, 0, stream>>>(rowstart, blocksum, cursor);
  k_scatter<<<dim3(1563, 6), 256, 0, stream>>>(em, cursor, csr_src);

  // ---- weight prep (single fused launch) ----
  k_prep<<<614, 256, 0, stream>>>(Wp, Wu, We, Wsrc, Wdst, asrc, adst, gatb,
                                  WpH, WpL, WuH, WuL, WeH, WeL, lbH, lbL,
                                  weff_s, weff_d, bsum);

  // ---- input projections (one fused MFMA launch, 3 segments) ----
  const int BLK0 = 0, BLK1 = (NPOST + 127) / 128, BLK2 = BLK1 + (NUSER + 127) / 128;
  const int BLKT = BLK2 + (NENT + 127) / 128;
  {
    GArgs gp;
    gp.s[0] = { x_post, nullptr, nullptr, WpH, WpL, bp, hA[0], NPOST, 768, BLK0 };
    gp.s[1] = { x_user, nullptr, nullptr, WuH, WuL, bu, hA[1], NUSER,  32, BLK1 };
    gp.s[2] = { x_ent,  nullptr, nullptr, WeH, WeL, be, hA[2], NENT,   64, BLK2 };
    k_mfgemm3<0, 0><<<BLKT, 256, 0, stream>>>(gp);
  }

  const int segoff[6] = {0, 24576, 40960, 49152, 73728, 90112};  // (l,type) B offsets

  float* cur[3] = {hA[0], hA[1], hA[2]};
  float* nxt[3] = {hB[0], hB[1], hB[2]};

  // agg grid: 105000 waves (4 rows each)
  const int AGG_BLOCKS = ((NDTOT + 3) / 4 * 64) / 256;

  for (int l = 0; l < 2; l++){
    k_al_all<<<(820000 + 255) / 256, 256, 0, stream>>>(cur[0], cur[1], cur[2],
                                                       weff_s, weff_d, als_all, ald_all, l);
    {
      AggArgs aa;
      aa.h[0] = cur[0]; aa.h[1] = cur[1]; aa.h[2] = cur[2];
      for (int i = 0; i < 3; i++){ aa.aggH[i] = aggHT[i]; aa.aggL[i] = aggLT[i]; }
      aa.als = als_all; aa.ald = ald_all;
      aa.rowstart = rowstart; aa.csr = csr_src;
      k_agg_all<<<AGG_BLOCKS, 256, 0, stream>>>(aa);
    }
    {
      GArgs ga;
      ga.s[0] = { nullptr, aggHT[0], aggLT[0], lbH + segoff[l*3+0], lbL + segoff[l*3+0],
                  bsum + (l*3+0)*64, nxt[0], NPOST, 384, BLK0 };
      ga.s[1] = { nullptr, aggHT[1], aggLT[1], lbH + segoff[l*3+1], lbL + segoff[l*3+1],
                  bsum + (l*3+1)*64, nxt[1], NUSER, 256, BLK1 };
      ga.s[2] = { nullptr, aggHT[2], aggLT[2], lbH + segoff[l*3+2], lbL + segoff[l*3+2],
                  bsum + (l*3+2)*64, nxt[2], NENT, 128, BLK2 };
      k_mfgemm3<1, 1><<<BLKT, 256, 0, stream>>>(ga);
    }
    for (int i = 0; i < 3; i++){ float* tmp = cur[i]; cur[i] = nxt[i]; nxt[i] = tmp; }
  }

  k_classifier<<<(NPOST + 255) / 256, 256, 0, stream>>>(cur[0], cw1, cb1, cw2, cb2, out, NPOST);
}

// Round 9
// 1126.070 us; speedup vs baseline: 1.0839x; 1.0202x over previous
//
#include <hip/hip_runtime.h>

#define NPOST 100000
#define NUSER 50000
#define NENT  20000
#define NDTOT 420000
#define ETOT  1550000
#define NSCANBLK 206

typedef short short8 __attribute__((ext_vector_type(8)));
typedef float f32x4 __attribute__((ext_vector_type(4)));
typedef unsigned short ushort4v __attribute__((ext_vector_type(4)));

static __device__ __forceinline__ unsigned short f2bf(float x){
  union { float f; unsigned u; } v; v.f = x;
  unsigned r = v.u + 0x7FFF + ((v.u >> 16) & 1);
  return (unsigned short)(r >> 16);
}
static __device__ __forceinline__ float bf2f(unsigned short h){
  union { unsigned u; float f; } v; v.u = ((unsigned)h) << 16;
  return v.f;
}

struct EdgeMeta {
  const int* src[6];
  const int* dst[6];
  int E[6];
  int degoff[6];
};

// ---------------- fused prep kernel ----------------

static __device__ __forceinline__ void d_split(const float* __restrict__ X,
                                               unsigned short* __restrict__ H,
                                               unsigned short* __restrict__ L, int i){
  float x = X[i];
  unsigned short h = f2bf(x);
  H[i] = h;
  L[i] = f2bf(x - bf2f(h));
}

static __device__ __forceinline__ void d_layerB(const float* __restrict__ Wsrc,
                                                unsigned short* __restrict__ H,
                                                unsigned short* __restrict__ L, int idx){
  const int off[6]  = {0, 24576, 40960, 49152, 73728, 90112};
  const int Ks[6]   = {384, 256, 128, 384, 256, 128};
  int seg = 5;
  #pragma unroll
  for (int s = 4; s >= 0; s--) if (idx < off[s + 1]) seg = s;
  int l = seg / 3, type = seg % 3;
  int K = Ks[seg];
  int rem = idx - off[seg];
  int n = rem / K, k = rem - n * K;
  int slot = k >> 7, head = (k >> 6) & 1, kk = k & 63;
  int rel;
  if (type == 0)      rel = (slot == 0) ? 0 : (slot == 1 ? 1 : 5);
  else if (type == 1) rel = (slot == 0) ? 3 : 4;
  else                rel = 2;
  int m = l * 6 + rel;
  float x = Wsrc[(size_t)m * 8192 + (head * 64 + n) * 64 + kk];
  unsigned short h = f2bf(x);
  H[idx] = h;
  L[idx] = f2bf(x - bf2f(h));
}

static __device__ __forceinline__ void d_weff(const float* __restrict__ W,
                                              const float* __restrict__ a,
                                              float* __restrict__ weff, int idx){
  int m = idx >> 7;
  int rem = idx & 127;
  int h = rem >> 6, k = rem & 63;
  const float* Wm = W + m * 8192;
  const float* am = a + m * 128;
  float acc = 0.f;
  #pragma unroll 8
  for (int c = 0; c < 64; c++)
    acc += Wm[(h * 64 + c) * 64 + k] * am[h * 64 + c];
  weff[idx] = acc;
}

static __device__ __forceinline__ void d_bias(const float* __restrict__ gatb,
                                              float* __restrict__ bsum, int idx){
  int c = idx & 63;
  int lt = idx >> 6;
  int l = lt / 3, t = lt % 3;
  float v;
  if (t == 0)      v = gatb[(l*6+0)*64+c] + gatb[(l*6+1)*64+c] + gatb[(l*6+5)*64+c];
  else if (t == 1) v = gatb[(l*6+3)*64+c] + gatb[(l*6+4)*64+c];
  else             v = gatb[(l*6+2)*64+c];
  bsum[lt * 64 + c] = v;
}

__global__ void k_prep(const float* __restrict__ Wp, const float* __restrict__ Wu,
                       const float* __restrict__ We, const float* __restrict__ Wsrc,
                       const float* __restrict__ Wdst, const float* __restrict__ asrc,
                       const float* __restrict__ adst, const float* __restrict__ gatb,
                       unsigned short* WpH, unsigned short* WpL,
                       unsigned short* WuH, unsigned short* WuL,
                       unsigned short* WeH, unsigned short* WeL,
                       unsigned short* lbH, unsigned short* lbL,
                       float* weff_s, float* weff_d, float* bsum){
  int idx = blockIdx.x * 256 + threadIdx.x;
  if (idx < 49152)       d_split(Wp, WpH, WpL, idx);
  else if (idx < 51200)  d_split(Wu, WuH, WuL, idx - 49152);
  else if (idx < 55296)  d_split(We, WeH, WeL, idx - 51200);
  else if (idx < 153600) d_layerB(Wsrc, lbH, lbL, idx - 55296);
  else if (idx < 155136) d_weff(Wsrc, asrc, weff_s, idx - 153600);
  else if (idx < 156672) d_weff(Wdst, adst, weff_d, idx - 155136);
  else if (idx < 157056) d_bias(gatb, bsum, idx - 156672);
}

// ---------------- CSR build ----------------

__global__ void k_hist(EdgeMeta em, int* __restrict__ deg){
  int r = blockIdx.y;
  int e = blockIdx.x * blockDim.x + threadIdx.x;
  if (e >= em.E[r]) return;
  atomicAdd(&deg[em.degoff[r] + em.dst[r][e]], 1);
}

__global__ __launch_bounds__(256) void k_scanA(const int* __restrict__ deg,
                                               int* __restrict__ rowstart,
                                               int* __restrict__ blocksum){
  __shared__ int sums[256];
  int t = threadIdx.x;
  int base = blockIdx.x * 2048 + t * 8;
  int v[8]; int s = 0;
  #pragma unroll
  for (int i = 0; i < 8; i++){
    int j = base + i;
    v[i] = (j < NDTOT) ? deg[j] : 0;
    s += v[i];
  }
  sums[t] = s;
  __syncthreads();
  for (int off = 1; off < 256; off <<= 1){
    int x = (t >= off) ? sums[t - off] : 0;
    __syncthreads();
    sums[t] += x;
    __syncthreads();
  }
  int excl = (t > 0) ? sums[t - 1] : 0;
  if (t == 255) blocksum[blockIdx.x] = sums[255];
  int run = excl;
  #pragma unroll
  for (int i = 0; i < 8; i++){
    int j = base + i;
    if (j < NDTOT) rowstart[j] = run;
    run += v[i];
  }
}

__global__ __launch_bounds__(256) void k_scanB(int* __restrict__ blocksum){
  __shared__ int s[256];
  int t = threadIdx.x;
  s[t] = (t < NSCANBLK) ? blocksum[t] : 0;
  __syncthreads();
  for (int off = 1; off < 256; off <<= 1){
    int x = (t >= off) ? s[t - off] : 0;
    __syncthreads();
    s[t] += x;
    __syncthreads();
  }
  int excl = (t > 0) ? s[t - 1] : 0;
  if (t < NSCANBLK) blocksum[t] = excl;
}

// scanC also initializes cursor (folds the old D2D memcpy)
__global__ void k_scanC(int* __restrict__ rowstart, const int* __restrict__ blocksum,
                        int* __restrict__ cursor){
  int j = blockIdx.x * blockDim.x + threadIdx.x;
  if (j < NDTOT){
    int v = rowstart[j] + blocksum[j >> 11];
    rowstart[j] = v;
    cursor[j] = v;
  }
  if (j == 0) rowstart[NDTOT] = ETOT;
}

__global__ void k_scatter(EdgeMeta em, int* __restrict__ cursor, int* __restrict__ csr_src){
  int r = blockIdx.y;
  int e = blockIdx.x * blockDim.x + threadIdx.x;
  if (e >= em.E[r]) return;
  int d = em.dst[r][e];
  int pos = atomicAdd(&cursor[em.degoff[r] + d], 1);
  csr_src[pos] = em.src[r][e];
}

// ---------------- fused attention logits ----------------
// src-side jobs: 400000 rows laid out [pub:50k user][rep:50k user][con:100k post]
//                                     [int:50k user][fol:50k user][sim:100k post]
// dst-side jobs: 420000 rows in global CSR row order (degoff layout)

__global__ void k_al_all(const float* __restrict__ h_post, const float* __restrict__ h_user,
                         const float* __restrict__ h_ent,
                         const float* __restrict__ weff_s, const float* __restrict__ weff_d,
                         float* __restrict__ als_all, float* __restrict__ ald_all, int l){
  int idx = blockIdx.x * blockDim.x + threadIdx.x;
  if (idx >= 820000) return;
  const float* h; const float* w; float* out; int node;
  if (idx < 400000){
    int r;
    if (idx < 50000)       { r = 0; node = idx;          h = h_user; }
    else if (idx < 100000) { r = 1; node = idx - 50000;  h = h_user; }
    else if (idx < 200000) { r = 2; node = idx - 100000; h = h_post; }
    else if (idx < 250000) { r = 3; node = idx - 200000; h = h_user; }
    else if (idx < 300000) { r = 4; node = idx - 250000; h = h_user; }
    else                   { r = 5; node = idx - 300000; h = h_post; }
    w = weff_s + (l * 6 + r) * 128;
    out = als_all + (size_t)idx * 2;
  } else {
    int j = idx - 400000;
    int r;
    if (j < 100000)        { r = 0; node = j;          h = h_post; }
    else if (j < 200000)   { r = 1; node = j - 100000; h = h_post; }
    else if (j < 220000)   { r = 2; node = j - 200000; h = h_ent;  }
    else if (j < 270000)   { r = 3; node = j - 220000; h = h_user; }
    else if (j < 320000)   { r = 4; node = j - 270000; h = h_user; }
    else                   { r = 5; node = j - 320000; h = h_post; }
    w = weff_d + (l * 6 + r) * 128;
    out = ald_all + (size_t)j * 2;
  }
  const float4* hr = (const float4*)(h + (size_t)node * 64);
  const float4* w0 = (const float4*)w;
  const float4* w1 = (const float4*)(w + 64);
  float a0 = 0.f, a1 = 0.f;
  #pragma unroll
  for (int q = 0; q < 16; q++){
    float4 v = hr[q];
    float4 x0 = w0[q], x1 = w1[q];
    a0 += v.x*x0.x + v.y*x0.y + v.z*x0.z + v.w*x0.w;
    a1 += v.x*x1.x + v.y*x1.y + v.z*x1.z + v.w*x1.w;
  }
  out[0] = a0;
  out[1] = a1;
}

// ---------------- LDS swizzle (shared by both GEMM kernels) ----------------
// element (row,k) of a 32-k chunk at row*32 + (((k>>3)^((row>>2)&3))<<3) + (k&7)

static __device__ __forceinline__ int swz(int row, int k){
  return row * 32 + ((((k >> 3) ^ ((row >> 2) & 3))) << 3) + (k & 7);
}

// ---------------- projection MFMA GEMM (3 fused segments, fp32 A) ----------------
// Tile 128 rows x 64 cols, K-chunk 32, 4 waves; 16x16x32 bf16 MFMA, 3-MFMA split.

struct GSeg {
  const float* A32;
  const unsigned short* BH;
  const unsigned short* BL;
  const float* bias;
  float* C;
  int N; int K; int blk0;
};
struct GArgs { GSeg s[3]; };

__global__ __launch_bounds__(256) void k_mfgemm3(GArgs G){
  __shared__ __align__(16) unsigned short sAh[128 * 32];
  __shared__ __align__(16) unsigned short sAl[128 * 32];
  __shared__ __align__(16) unsigned short sBh[64 * 32];
  __shared__ __align__(16) unsigned short sBl[64 * 32];
  int b = blockIdx.x;
  GSeg sg = G.s[0];
  if (b >= G.s[1].blk0) sg = G.s[1];
  if (b >= G.s[2].blk0) sg = G.s[2];
  const int N = sg.N, K = sg.K;
  int t = threadIdx.x;
  int w = t >> 6, lane = t & 63;
  int q = lane >> 4, m15 = lane & 15;
  int r0 = blockIdx.x == b ? (b - sg.blk0) * 128 : 0;
  f32x4 acc[2][4];
  #pragma unroll
  for (int i = 0; i < 2; i++)
    #pragma unroll
    for (int j = 0; j < 4; j++)
      acc[i][j] = (f32x4){0.f, 0.f, 0.f, 0.f};

  int arow = t >> 1, akb = (t & 1) * 16;
  int brow = t >> 2, bkb = (t & 3) * 8;
  int gr = r0 + arow;
  bool avalid = gr < N;

  for (int k0 = 0; k0 < K; k0 += 32){
    float v[16];
    if (avalid){
      const float4* ap = (const float4*)(sg.A32 + (size_t)gr * K + k0 + akb);
      #pragma unroll
      for (int i = 0; i < 4; i++){
        float4 f = ap[i];
        v[i*4+0] = f.x; v[i*4+1] = f.y; v[i*4+2] = f.z; v[i*4+3] = f.w;
      }
    } else {
      #pragma unroll
      for (int i = 0; i < 16; i++) v[i] = 0.f;
    }
    short8 h0, h1, l0, l1;
    #pragma unroll
    for (int i = 0; i < 8; i++){
      unsigned short hh = f2bf(v[i]);
      h0[i] = (short)hh; l0[i] = (short)f2bf(v[i] - bf2f(hh));
      unsigned short hj = f2bf(v[8+i]);
      h1[i] = (short)hj; l1[i] = (short)f2bf(v[8+i] - bf2f(hj));
    }
    *(short8*)(sAh + swz(arow, akb))     = h0;
    *(short8*)(sAh + swz(arow, akb + 8)) = h1;
    *(short8*)(sAl + swz(arow, akb))     = l0;
    *(short8*)(sAl + swz(arow, akb + 8)) = l1;
    *(short8*)(sBh + swz(brow, bkb)) = *(const short8*)(sg.BH + (size_t)brow * K + k0 + bkb);
    *(short8*)(sBl + swz(brow, bkb)) = *(const short8*)(sg.BL + (size_t)brow * K + k0 + bkb);
    __syncthreads();
    short8 ah[2], al_[2];
    #pragma unroll
    for (int i = 0; i < 2; i++){
      int mrow = w * 32 + i * 16 + m15;
      ah[i]  = *(const short8*)(sAh + swz(mrow, q * 8));
      al_[i] = *(const short8*)(sAl + swz(mrow, q * 8));
    }
    #pragma unroll
    for (int j = 0; j < 4; j++){
      int bn = j * 16 + m15;
      short8 bh = *(const short8*)(sBh + swz(bn, q * 8));
      short8 bl = *(const short8*)(sBl + swz(bn, q * 8));
      #pragma unroll
      for (int i = 0; i < 2; i++){
        acc[i][j] = __builtin_amdgcn_mfma_f32_16x16x32_bf16(ah[i],  bh, acc[i][j], 0, 0, 0);
        acc[i][j] = __builtin_amdgcn_mfma_f32_16x16x32_bf16(ah[i],  bl, acc[i][j], 0, 0, 0);
        acc[i][j] = __builtin_amdgcn_mfma_f32_16x16x32_bf16(al_[i], bh, acc[i][j], 0, 0, 0);
      }
    }
    __syncthreads();
  }
  #pragma unroll
  for (int j = 0; j < 4; j++){
    int col = j * 16 + m15;
    float bv = sg.bias[col];
    #pragma unroll
    for (int i = 0; i < 2; i++){
      #pragma unroll
      for (int r = 0; r < 4; r++){
        int row = r0 + w * 32 + i * 16 + q * 4 + r;
        if (row < N){
          float vv = acc[i][j][r] + bv;
          sg.C[(size_t)row * 64 + col] = vv;
        }
      }
    }
  }
}

// ---------------- fused GAT-aggregate + MFMA GEMM (layer step) ----------------
// Per block: 64 dst rows of one node type. Per K-slot (relation):
//   aggregate phase: 16 groups x 16 lanes run the proven k_agg_all edge loop
//     (identical gathers / fmaf order / 0.5/s / f2bf split) writing split bf16
//     directly into the LDS chunk buffers -> agg HBM round trip eliminated.
//   MFMA phase: 4 K-chunks; B staged per chunk; global chunk order identical
//     to the unfused version -> bitwise-identical C.
// LDS: A 16+16 KB, B 4+4 KB = 40 KB -> 4 blocks/CU.

struct GGSeg {
  const unsigned short* BH;
  const unsigned short* BL;
  const float* bias;
  float* C;
  int N; int K; int blk0; int ty;
};
struct GGArgs {
  GGSeg s[3];
  const float* h[3];       // cur h per node type (post, user, ent)
  const float* als;
  const float* ald;
  const int* rowstart;
  const int* csr;
};

__global__ __launch_bounds__(256) void k_gatgemm(GGArgs G){
  __shared__ __align__(16) unsigned short sAh[4 * 64 * 32];
  __shared__ __align__(16) unsigned short sAl[4 * 64 * 32];
  __shared__ __align__(16) unsigned short sBh[64 * 32];
  __shared__ __align__(16) unsigned short sBl[64 * 32];
  int b = blockIdx.x;
  GGSeg sg = G.s[0];
  if (b >= G.s[1].blk0) sg = G.s[1];
  if (b >= G.s[2].blk0) sg = G.s[2];
  const int N = sg.N, K = sg.K, ty = sg.ty;
  int t = threadIdx.x;
  int w = t >> 6, lane = t & 63;
  int q = lane >> 4, m15 = lane & 15;
  int gid = t >> 4, lg = t & 15;        // 16 groups x 16 lanes
  int r0 = (b - sg.blk0) * 64;
  f32x4 acc[4];
  #pragma unroll
  for (int j = 0; j < 4; j++) acc[j] = (f32x4){0.f, 0.f, 0.f, 0.f};

  int brow = t >> 2, bkb = (t & 3) * 8;
  int nslots = K >> 7;
  const int relT[3][3]    = {{0,1,5},{3,4,0},{2,0,0}};
  const int stT[3][3]     = {{1,1,0},{1,1,0},{0,0,0}};
  const int alsoffT[3][3] = {{0,50000,300000},{200000,250000,0},{100000,0,0}};
  const int dgoT[6] = {0,100000,200000,220000,270000,320000};

  for (int s = 0; s < nslots; s++){
    int rel = relT[ty][s];
    const float* __restrict__ h = G.h[stT[ty][s]];
    const float* __restrict__ als = G.als + (size_t)alsoffT[ty][s] * 2;
    int dgo = dgoT[rel];
    // ---- aggregate 64 rows into LDS chunk buffers ----
    #pragma unroll
    for (int pass = 0; pass < 4; pass++){
      int rloc = pass * 16 + gid;
      int row = r0 + rloc;
      float4 a0v = {0.f,0.f,0.f,0.f}, a1v = {0.f,0.f,0.f,0.f};
      float s0 = 0.f, s1 = 0.f;
      if (row < N){
        int gw = dgo + row;
        float2 ad = *(const float2*)(G.ald + (size_t)gw * 2);
        int rs = G.rowstart[gw];
        int re = G.rowstart[gw + 1];
        if (re > rs){
          int sidx = G.csr[rs];
          float2 as = *(const float2*)(als + (size_t)sidx * 2);
          float4 hv = *(const float4*)(h + (size_t)sidx * 64 + lg * 4);
          for (int e = rs; e < re; e++){
            int nsidx = (e + 1 < re) ? G.csr[e + 1] : sidx;
            float2 nas = *(const float2*)(als + (size_t)nsidx * 2);
            float4 nhv = *(const float4*)(h + (size_t)nsidx * 64 + lg * 4);
            float e0 = as.x + ad.x, e1 = as.y + ad.y;
            e0 = e0 > 0.f ? e0 : 0.2f * e0;
            e1 = e1 > 0.f ? e1 : 0.2f * e1;
            float p0 = __expf(e0), p1 = __expf(e1);
            a0v.x = fmaf(p0, hv.x, a0v.x); a0v.y = fmaf(p0, hv.y, a0v.y);
            a0v.z = fmaf(p0, hv.z, a0v.z); a0v.w = fmaf(p0, hv.w, a0v.w);
            a1v.x = fmaf(p1, hv.x, a1v.x); a1v.y = fmaf(p1, hv.y, a1v.y);
            a1v.z = fmaf(p1, hv.z, a1v.z); a1v.w = fmaf(p1, hv.w, a1v.w);
            s0 += p0; s1 += p1;
            as = nas; hv = nhv; sidx = nsidx;
          }
        }
      }
      float rc0 = s0 > 0.f ? 0.5f / s0 : 0.f;
      float rc1 = s1 > 0.f ? 0.5f / s1 : 0.f;
      float v0x = a0v.x*rc0, v0y = a0v.y*rc0, v0z = a0v.z*rc0, v0w = a0v.w*rc0;
      float v1x = a1v.x*rc1, v1y = a1v.y*rc1, v1z = a1v.z*rc1, v1w = a1v.w*rc1;
      ushort4v h0v, h1v, l0v, l1v;
      h0v[0]=f2bf(v0x); h0v[1]=f2bf(v0y); h0v[2]=f2bf(v0z); h0v[3]=f2bf(v0w);
      h1v[0]=f2bf(v1x); h1v[1]=f2bf(v1y); h1v[2]=f2bf(v1z); h1v[3]=f2bf(v1w);
      l0v[0]=f2bf(v0x-bf2f(h0v[0])); l0v[1]=f2bf(v0y-bf2f(h0v[1]));
      l0v[2]=f2bf(v0z-bf2f(h0v[2])); l0v[3]=f2bf(v0w-bf2f(h0v[3]));
      l1v[0]=f2bf(v1x-bf2f(h1v[0])); l1v[1]=f2bf(v1y-bf2f(h1v[1]));
      l1v[2]=f2bf(v1z-bf2f(h1v[2])); l1v[3]=f2bf(v1w-bf2f(h1v[3]));
      int c0 = lg >> 3;               // (lg*4)>>5
      int kk = (lg * 4) & 31;
      *(ushort4v*)(sAh + c0*2048       + swz(rloc, kk)) = h0v;
      *(ushort4v*)(sAh + (2+c0)*2048   + swz(rloc, kk)) = h1v;
      *(ushort4v*)(sAl + c0*2048       + swz(rloc, kk)) = l0v;
      *(ushort4v*)(sAl + (2+c0)*2048   + swz(rloc, kk)) = l1v;
    }
    __syncthreads();
    // ---- 4 K-chunks of MFMA over this slot ----
    for (int c = 0; c < 4; c++){
      int gk = s * 128 + c * 32;
      *(short8*)(sBh + swz(brow, bkb)) = *(const short8*)(sg.BH + (size_t)brow * K + gk + bkb);
      *(short8*)(sBl + swz(brow, bkb)) = *(const short8*)(sg.BL + (size_t)brow * K + gk + bkb);
      __syncthreads();
      int mrow = w * 16 + m15;
      short8 ah  = *(const short8*)(sAh + c*2048 + swz(mrow, q * 8));
      short8 al_ = *(const short8*)(sAl + c*2048 + swz(mrow, q * 8));
      #pragma unroll
      for (int j = 0; j < 4; j++){
        int bn = j * 16 + m15;
        short8 bh = *(const short8*)(sBh + swz(bn, q * 8));
        short8 bl = *(const short8*)(sBl + swz(bn, q * 8));
        acc[j] = __builtin_amdgcn_mfma_f32_16x16x32_bf16(ah,  bh, acc[j], 0, 0, 0);
        acc[j] = __builtin_amdgcn_mfma_f32_16x16x32_bf16(ah,  bl, acc[j], 0, 0, 0);
        acc[j] = __builtin_amdgcn_mfma_f32_16x16x32_bf16(al_, bh, acc[j], 0, 0, 0);
      }
      __syncthreads();
    }
  }
  // ---- epilogue: bias + relu + store ----
  #pragma unroll
  for (int j = 0; j < 4; j++){
    int col = j * 16 + m15;
    float bv = sg.bias[col];
    #pragma unroll
    for (int r = 0; r < 4; r++){
      int row = r0 + w * 16 + q * 4 + r;
      if (row < N){
        float vv = acc[j][r] + bv;
        vv = vv > 0.f ? vv : 0.f;
        sg.C[(size_t)row * 64 + col] = vv;
      }
    }
  }
}

// ---------------- classifier head ----------------

__global__ __launch_bounds__(256) void k_classifier(const float* __restrict__ hpost,
                                                    const float* __restrict__ w1,
                                                    const float* __restrict__ b1,
                                                    const float* __restrict__ w2,
                                                    const float* __restrict__ b2,
                                                    float* __restrict__ out, int N){
  __shared__ float w1s[32 * 64];
  __shared__ float b1s[32];
  __shared__ float w2s[32];
  for (int i = threadIdx.x; i < 2048; i += 256) w1s[i] = w1[i];
  if (threadIdx.x < 32){
    b1s[threadIdx.x] = b1[threadIdx.x];
    w2s[threadIdx.x] = w2[threadIdx.x];
  }
  __syncthreads();
  float bias2 = b2[0];
  for (int n = blockIdx.x * blockDim.x + threadIdx.x; n < N; n += gridDim.x * blockDim.x){
    float4 hr[16];
    const float4* hp = (const float4*)(hpost + (size_t)n * 64);
    #pragma unroll
    for (int q = 0; q < 16; q++) hr[q] = hp[q];
    float o = bias2;
    #pragma unroll 4
    for (int j = 0; j < 32; j++){
      float dacc = b1s[j];
      const float4* wr = (const float4*)(w1s + j * 64);
      #pragma unroll
      for (int q = 0; q < 16; q++){
        float4 w = wr[q]; float4 v = hr[q];
        dacc += w.x*v.x + w.y*v.y + w.z*v.z + w.w*v.w;
      }
      dacc = dacc > 0.f ? dacc : 0.f;
      o += w2s[j] * dacc;
    }
    out[n] = o;
  }
}

// ---------------- host ----------------

static inline size_t align256(size_t x){ return (x + 255) & ~(size_t)255; }

extern "C" void kernel_launch(void* const* d_in, const int* in_sizes, int n_in,
                              void* d_out, int out_size, void* d_ws, size_t ws_size,
                              hipStream_t stream){
  (void)in_sizes; (void)n_in; (void)out_size; (void)ws_size;
  const float* x_post = (const float*)d_in[0];
  const float* x_user = (const float*)d_in[1];
  const float* x_ent  = (const float*)d_in[2];
  EdgeMeta em;
  for (int r = 0; r < 6; r++){
    em.src[r] = (const int*)d_in[3 + 2*r];
    em.dst[r] = (const int*)d_in[4 + 2*r];
  }
  const int Earr[6] = {100000, 200000, 200000, 400000, 400000, 250000};
  const int dgo[6]  = {0, 100000, 200000, 220000, 270000, 320000};
  for (int r = 0; r < 6; r++){ em.E[r] = Earr[r]; em.degoff[r] = dgo[r]; }

  const float* Wp   = (const float*)d_in[15]; const float* bp = (const float*)d_in[16];
  const float* Wu   = (const float*)d_in[17]; const float* bu = (const float*)d_in[18];
  const float* We   = (const float*)d_in[19]; const float* be = (const float*)d_in[20];
  const float* Wsrc = (const float*)d_in[21];
  const float* Wdst = (const float*)d_in[22];
  const float* asrc = (const float*)d_in[23];
  const float* adst = (const float*)d_in[24];
  const float* gatb = (const float*)d_in[25];
  const float* cw1  = (const float*)d_in[26]; const float* cb1 = (const float*)d_in[27];
  const float* cw2  = (const float*)d_in[28]; const float* cb2 = (const float*)d_in[29];
  float* out = (float*)d_out;

  const int NN[3] = {NPOST, NUSER, NENT};

  // ---- workspace ----
  char* p = (char*)d_ws;
  auto alloc = [&](size_t bytes){ char* r = p; p += align256(bytes); return r; };
  float* hA[3]; float* hB[3];
  for (int i = 0; i < 3; i++) hA[i] = (float*)alloc((size_t)NN[i] * 64 * 4);
  for (int i = 0; i < 3; i++) hB[i] = (float*)alloc((size_t)NN[i] * 64 * 4);
  float* als_all = (float*)alloc((size_t)400000 * 2 * 4);
  float* ald_all = (float*)alloc((size_t)NDTOT * 2 * 4);
  float* weff_s = (float*)alloc(1536 * 4);
  float* weff_d = (float*)alloc(1536 * 4);
  unsigned short* WpH = (unsigned short*)alloc(768 * 64 * 2);
  unsigned short* WpL = (unsigned short*)alloc(768 * 64 * 2);
  unsigned short* WuH = (unsigned short*)alloc(32 * 64 * 2);
  unsigned short* WuL = (unsigned short*)alloc(32 * 64 * 2);
  unsigned short* WeH = (unsigned short*)alloc(64 * 64 * 2);
  unsigned short* WeL = (unsigned short*)alloc(64 * 64 * 2);
  unsigned short* lbH = (unsigned short*)alloc(98304 * 2);
  unsigned short* lbL = (unsigned short*)alloc(98304 * 2);
  float* bsum   = (float*)alloc(6 * 64 * 4);
  int* deg      = (int*)alloc((size_t)NDTOT * 4);
  int* rowstart = (int*)alloc((size_t)(NDTOT + 1) * 4);
  int* cursor   = (int*)alloc((size_t)NDTOT * 4);
  int* csr_src  = (int*)alloc((size_t)ETOT * 4);
  int* blocksum = (int*)alloc((size_t)NSCANBLK * 4);

  // ---- CSR build (layer-invariant) ----
  hipMemsetAsync(deg, 0, (size_t)NDTOT * 4, stream);
  k_hist<<<dim3(1563, 6), 256, 0, stream>>>(em, deg);
  k_scanA<<<NSCANBLK, 256, 0, stream>>>(deg, rowstart, blocksum);
  k_scanB<<<1, 256, 0, stream>>>(blocksum);
  k_scanC<<<(NDTOT + 255) / 256, 256, 0, stream>>>(rowstart, blocksum, cursor);
  k_scatter<<<dim3(1563, 6), 256, 0, stream>>>(em, cursor, csr_src);

  // ---- weight prep (single fused launch) ----
  k_prep<<<614, 256, 0, stream>>>(Wp, Wu, We, Wsrc, Wdst, asrc, adst, gatb,
                                  WpH, WpL, WuH, WuL, WeH, WeL, lbH, lbL,
                                  weff_s, weff_d, bsum);

  // ---- input projections (one fused MFMA launch, 3 segments, BM=128) ----
  const int PBLK1 = (NPOST + 127) / 128, PBLK2 = PBLK1 + (NUSER + 127) / 128;
  const int PBLKT = PBLK2 + (NENT + 127) / 128;
  {
    GArgs gp;
    gp.s[0] = { x_post, WpH, WpL, bp, hA[0], NPOST, 768, 0 };
    gp.s[1] = { x_user, WuH, WuL, bu, hA[1], NUSER,  32, PBLK1 };
    gp.s[2] = { x_ent,  WeH, WeL, be, hA[2], NENT,   64, PBLK2 };
    k_mfgemm3<<<PBLKT, 256, 0, stream>>>(gp);
  }

  const int segoff[6] = {0, 24576, 40960, 49152, 73728, 90112};  // (l,type) B offsets

  float* cur[3] = {hA[0], hA[1], hA[2]};
  float* nxt[3] = {hB[0], hB[1], hB[2]};

  // fused layer GEMM grid (BM=64)
  const int GBLK1 = (NPOST + 63) / 64, GBLK2 = GBLK1 + (NUSER + 63) / 64;
  const int GBLKT = GBLK2 + (NENT + 63) / 64;

  for (int l = 0; l < 2; l++){
    k_al_all<<<(820000 + 255) / 256, 256, 0, stream>>>(cur[0], cur[1], cur[2],
                                                       weff_s, weff_d, als_all, ald_all, l);
    {
      GGArgs gg;
      gg.s[0] = { lbH + segoff[l*3+0], lbL + segoff[l*3+0], bsum + (l*3+0)*64,
                  nxt[0], NPOST, 384, 0, 0 };
      gg.s[1] = { lbH + segoff[l*3+1], lbL + segoff[l*3+1], bsum + (l*3+1)*64,
                  nxt[1], NUSER, 256, GBLK1, 1 };
      gg.s[2] = { lbH + segoff[l*3+2], lbL + segoff[l*3+2], bsum + (l*3+2)*64,
                  nxt[2], NENT, 128, GBLK2, 2 };
      gg.h[0] = cur[0]; gg.h[1] = cur[1]; gg.h[2] = cur[2];
      gg.als = als_all; gg.ald = ald_all;
      gg.rowstart = rowstart; gg.csr = csr_src;
      k_gatgemm<<<GBLKT, 256, 0, stream>>>(gg);
    }
    for (int i = 0; i < 3; i++){ float* tmp = cur[i]; cur[i] = nxt[i]; nxt[i] = tmp; }
  }

  k_classifier<<<(NPOST + 255) / 256, 256, 0, stream>>>(cur[0], cw1, cb1, cw2, cb2, out, NPOST);
}

// Round 10
// 1098.802 us; speedup vs baseline: 1.1108x; 1.0248x over previous
//
#include <hip/hip_runtime.h>

#define NPOST 100000
#define NUSER 50000
#define NENT  20000
#define NDTOT 420000
#define ETOT  1550000
#define NSCANBLK 206

typedef short short8 __attribute__((ext_vector_type(8)));
typedef float f32x4 __attribute__((ext_vector_type(4)));
typedef unsigned short ushort4v __attribute__((ext_vector_type(4)));

static __device__ __forceinline__ unsigned short f2bf(float x){
  union { float f; unsigned u; } v; v.f = x;
  unsigned r = v.u + 0x7FFF + ((v.u >> 16) & 1);
  return (unsigned short)(r >> 16);
}
static __device__ __forceinline__ float bf2f(unsigned short h){
  union { unsigned u; float f; } v; v.u = ((unsigned)h) << 16;
  return v.f;
}

struct EdgeMeta {
  const int* src[6];
  const int* dst[6];
  int E[6];
  int degoff[6];
};

// ---------------- fused prep kernel ----------------

static __device__ __forceinline__ void d_split(const float* __restrict__ X,
                                               unsigned short* __restrict__ H,
                                               unsigned short* __restrict__ L, int i){
  float x = X[i];
  unsigned short h = f2bf(x);
  H[i] = h;
  L[i] = f2bf(x - bf2f(h));
}

static __device__ __forceinline__ void d_layerB(const float* __restrict__ Wsrc,
                                                unsigned short* __restrict__ H,
                                                unsigned short* __restrict__ L, int idx){
  const int off[6]  = {0, 24576, 40960, 49152, 73728, 90112};
  const int Ks[6]   = {384, 256, 128, 384, 256, 128};
  int seg = 5;
  #pragma unroll
  for (int s = 4; s >= 0; s--) if (idx < off[s + 1]) seg = s;
  int l = seg / 3, type = seg % 3;
  int K = Ks[seg];
  int rem = idx - off[seg];
  int n = rem / K, k = rem - n * K;
  int slot = k >> 7, head = (k >> 6) & 1, kk = k & 63;
  int rel;
  if (type == 0)      rel = (slot == 0) ? 0 : (slot == 1 ? 1 : 5);
  else if (type == 1) rel = (slot == 0) ? 3 : 4;
  else                rel = 2;
  int m = l * 6 + rel;
  float x = Wsrc[(size_t)m * 8192 + (head * 64 + n) * 64 + kk];
  unsigned short h = f2bf(x);
  H[idx] = h;
  L[idx] = f2bf(x - bf2f(h));
}

static __device__ __forceinline__ void d_weff(const float* __restrict__ W,
                                              const float* __restrict__ a,
                                              float* __restrict__ weff, int idx){
  int m = idx >> 7;
  int rem = idx & 127;
  int h = rem >> 6, k = rem & 63;
  const float* Wm = W + m * 8192;
  const float* am = a + m * 128;
  float acc = 0.f;
  #pragma unroll 8
  for (int c = 0; c < 64; c++)
    acc += Wm[(h * 64 + c) * 64 + k] * am[h * 64 + c];
  weff[idx] = acc;
}

static __device__ __forceinline__ void d_bias(const float* __restrict__ gatb,
                                              float* __restrict__ bsum, int idx){
  int c = idx & 63;
  int lt = idx >> 6;
  int l = lt / 3, t = lt % 3;
  float v;
  if (t == 0)      v = gatb[(l*6+0)*64+c] + gatb[(l*6+1)*64+c] + gatb[(l*6+5)*64+c];
  else if (t == 1) v = gatb[(l*6+3)*64+c] + gatb[(l*6+4)*64+c];
  else             v = gatb[(l*6+2)*64+c];
  bsum[lt * 64 + c] = v;
}

__global__ void k_prep(const float* __restrict__ Wp, const float* __restrict__ Wu,
                       const float* __restrict__ We, const float* __restrict__ Wsrc,
                       const float* __restrict__ Wdst, const float* __restrict__ asrc,
                       const float* __restrict__ adst, const float* __restrict__ gatb,
                       unsigned short* WpH, unsigned short* WpL,
                       unsigned short* WuH, unsigned short* WuL,
                       unsigned short* WeH, unsigned short* WeL,
                       unsigned short* lbH, unsigned short* lbL,
                       float* weff_s, float* weff_d, float* bsum){
  int idx = blockIdx.x * 256 + threadIdx.x;
  if (idx < 49152)       d_split(Wp, WpH, WpL, idx);
  else if (idx < 51200)  d_split(Wu, WuH, WuL, idx - 49152);
  else if (idx < 55296)  d_split(We, WeH, WeL, idx - 51200);
  else if (idx < 153600) d_layerB(Wsrc, lbH, lbL, idx - 55296);
  else if (idx < 155136) d_weff(Wsrc, asrc, weff_s, idx - 153600);
  else if (idx < 156672) d_weff(Wdst, adst, weff_d, idx - 155136);
  else if (idx < 157056) d_bias(gatb, bsum, idx - 156672);
}

// ---------------- CSR build ----------------

__global__ void k_hist(EdgeMeta em, int* __restrict__ deg){
  int r = blockIdx.y;
  int e = blockIdx.x * blockDim.x + threadIdx.x;
  if (e >= em.E[r]) return;
  atomicAdd(&deg[em.degoff[r] + em.dst[r][e]], 1);
}

__global__ __launch_bounds__(256) void k_scanA(const int* __restrict__ deg,
                                               int* __restrict__ rowstart,
                                               int* __restrict__ blocksum){
  __shared__ int sums[256];
  int t = threadIdx.x;
  int base = blockIdx.x * 2048 + t * 8;
  int v[8]; int s = 0;
  #pragma unroll
  for (int i = 0; i < 8; i++){
    int j = base + i;
    v[i] = (j < NDTOT) ? deg[j] : 0;
    s += v[i];
  }
  sums[t] = s;
  __syncthreads();
  for (int off = 1; off < 256; off <<= 1){
    int x = (t >= off) ? sums[t - off] : 0;
    __syncthreads();
    sums[t] += x;
    __syncthreads();
  }
  int excl = (t > 0) ? sums[t - 1] : 0;
  if (t == 255) blocksum[blockIdx.x] = sums[255];
  int run = excl;
  #pragma unroll
  for (int i = 0; i < 8; i++){
    int j = base + i;
    if (j < NDTOT) rowstart[j] = run;
    run += v[i];
  }
}

__global__ __launch_bounds__(256) void k_scanB(int* __restrict__ blocksum){
  __shared__ int s[256];
  int t = threadIdx.x;
  s[t] = (t < NSCANBLK) ? blocksum[t] : 0;
  __syncthreads();
  for (int off = 1; off < 256; off <<= 1){
    int x = (t >= off) ? s[t - off] : 0;
    __syncthreads();
    s[t] += x;
    __syncthreads();
  }
  int excl = (t > 0) ? s[t - 1] : 0;
  if (t < NSCANBLK) blocksum[t] = excl;
}

// scanC also initializes cursor (folds the old D2D memcpy)
__global__ void k_scanC(int* __restrict__ rowstart, const int* __restrict__ blocksum,
                        int* __restrict__ cursor){
  int j = blockIdx.x * blockDim.x + threadIdx.x;
  if (j < NDTOT){
    int v = rowstart[j] + blocksum[j >> 11];
    rowstart[j] = v;
    cursor[j] = v;
  }
  if (j == 0) rowstart[NDTOT] = ETOT;
}

__global__ void k_scatter(EdgeMeta em, int* __restrict__ cursor, int* __restrict__ csr_src){
  int r = blockIdx.y;
  int e = blockIdx.x * blockDim.x + threadIdx.x;
  if (e >= em.E[r]) return;
  int d = em.dst[r][e];
  int pos = atomicAdd(&cursor[em.degoff[r] + d], 1);
  csr_src[pos] = em.src[r][e];
}

// ---------------- fused attention logits ----------------
// src-side jobs: 400000 rows laid out [pub:50k user][rep:50k user][con:100k post]
//                                     [int:50k user][fol:50k user][sim:100k post]
// dst-side jobs: 420000 rows in global CSR row order (degoff layout)

__global__ void k_al_all(const float* __restrict__ h_post, const float* __restrict__ h_user,
                         const float* __restrict__ h_ent,
                         const float* __restrict__ weff_s, const float* __restrict__ weff_d,
                         float* __restrict__ als_all, float* __restrict__ ald_all, int l){
  int idx = blockIdx.x * blockDim.x + threadIdx.x;
  if (idx >= 820000) return;
  const float* h; const float* w; float* out; int node;
  if (idx < 400000){
    int r;
    if (idx < 50000)       { r = 0; node = idx;          h = h_user; }
    else if (idx < 100000) { r = 1; node = idx - 50000;  h = h_user; }
    else if (idx < 200000) { r = 2; node = idx - 100000; h = h_post; }
    else if (idx < 250000) { r = 3; node = idx - 200000; h = h_user; }
    else if (idx < 300000) { r = 4; node = idx - 250000; h = h_user; }
    else                   { r = 5; node = idx - 300000; h = h_post; }
    w = weff_s + (l * 6 + r) * 128;
    out = als_all + (size_t)idx * 2;
  } else {
    int j = idx - 400000;
    int r;
    if (j < 100000)        { r = 0; node = j;          h = h_post; }
    else if (j < 200000)   { r = 1; node = j - 100000; h = h_post; }
    else if (j < 220000)   { r = 2; node = j - 200000; h = h_ent;  }
    else if (j < 270000)   { r = 3; node = j - 220000; h = h_user; }
    else if (j < 320000)   { r = 4; node = j - 270000; h = h_user; }
    else                   { r = 5; node = j - 320000; h = h_post; }
    w = weff_d + (l * 6 + r) * 128;
    out = ald_all + (size_t)j * 2;
  }
  const float4* hr = (const float4*)(h + (size_t)node * 64);
  const float4* w0 = (const float4*)w;
  const float4* w1 = (const float4*)(w + 64);
  float a0 = 0.f, a1 = 0.f;
  #pragma unroll
  for (int q = 0; q < 16; q++){
    float4 v = hr[q];
    float4 x0 = w0[q], x1 = w1[q];
    a0 += v.x*x0.x + v.y*x0.y + v.z*x0.z + v.w*x0.w;
    a1 += v.x*x1.x + v.y*x1.y + v.z*x1.z + v.w*x1.w;
  }
  out[0] = a0;
  out[1] = a1;
}

// ---------------- LDS swizzle (shared by both GEMM kernels) ----------------
// element (row,k) of a 32-k chunk at row*32 + (((k>>3)^((row>>2)&3))<<3) + (k&7)

static __device__ __forceinline__ int swz(int row, int k){
  return row * 32 + ((((k >> 3) ^ ((row >> 2) & 3))) << 3) + (k & 7);
}

// ---------------- projection MFMA GEMM (3 fused segments, fp32 A) ----------------
// Tile 128 rows x 64 cols, K-chunk 32, 4 waves; 16x16x32 bf16 MFMA, 3-MFMA split.

struct GSeg {
  const float* A32;
  const unsigned short* BH;
  const unsigned short* BL;
  const float* bias;
  float* C;
  int N; int K; int blk0;
};
struct GArgs { GSeg s[3]; };

__global__ __launch_bounds__(256) void k_mfgemm3(GArgs G){
  __shared__ __align__(16) unsigned short sAh[128 * 32];
  __shared__ __align__(16) unsigned short sAl[128 * 32];
  __shared__ __align__(16) unsigned short sBh[64 * 32];
  __shared__ __align__(16) unsigned short sBl[64 * 32];
  int b = blockIdx.x;
  GSeg sg = G.s[0];
  if (b >= G.s[1].blk0) sg = G.s[1];
  if (b >= G.s[2].blk0) sg = G.s[2];
  const int N = sg.N, K = sg.K;
  int t = threadIdx.x;
  int w = t >> 6, lane = t & 63;
  int q = lane >> 4, m15 = lane & 15;
  int r0 = blockIdx.x == b ? (b - sg.blk0) * 128 : 0;
  f32x4 acc[2][4];
  #pragma unroll
  for (int i = 0; i < 2; i++)
    #pragma unroll
    for (int j = 0; j < 4; j++)
      acc[i][j] = (f32x4){0.f, 0.f, 0.f, 0.f};

  int arow = t >> 1, akb = (t & 1) * 16;
  int brow = t >> 2, bkb = (t & 3) * 8;
  int gr = r0 + arow;
  bool avalid = gr < N;

  for (int k0 = 0; k0 < K; k0 += 32){
    float v[16];
    if (avalid){
      const float4* ap = (const float4*)(sg.A32 + (size_t)gr * K + k0 + akb);
      #pragma unroll
      for (int i = 0; i < 4; i++){
        float4 f = ap[i];
        v[i*4+0] = f.x; v[i*4+1] = f.y; v[i*4+2] = f.z; v[i*4+3] = f.w;
      }
    } else {
      #pragma unroll
      for (int i = 0; i < 16; i++) v[i] = 0.f;
    }
    short8 h0, h1, l0, l1;
    #pragma unroll
    for (int i = 0; i < 8; i++){
      unsigned short hh = f2bf(v[i]);
      h0[i] = (short)hh; l0[i] = (short)f2bf(v[i] - bf2f(hh));
      unsigned short hj = f2bf(v[8+i]);
      h1[i] = (short)hj; l1[i] = (short)f2bf(v[8+i] - bf2f(hj));
    }
    *(short8*)(sAh + swz(arow, akb))     = h0;
    *(short8*)(sAh + swz(arow, akb + 8)) = h1;
    *(short8*)(sAl + swz(arow, akb))     = l0;
    *(short8*)(sAl + swz(arow, akb + 8)) = l1;
    *(short8*)(sBh + swz(brow, bkb)) = *(const short8*)(sg.BH + (size_t)brow * K + k0 + bkb);
    *(short8*)(sBl + swz(brow, bkb)) = *(const short8*)(sg.BL + (size_t)brow * K + k0 + bkb);
    __syncthreads();
    short8 ah[2], al_[2];
    #pragma unroll
    for (int i = 0; i < 2; i++){
      int mrow = w * 32 + i * 16 + m15;
      ah[i]  = *(const short8*)(sAh + swz(mrow, q * 8));
      al_[i] = *(const short8*)(sAl + swz(mrow, q * 8));
    }
    #pragma unroll
    for (int j = 0; j < 4; j++){
      int bn = j * 16 + m15;
      short8 bh = *(const short8*)(sBh + swz(bn, q * 8));
      short8 bl = *(const short8*)(sBl + swz(bn, q * 8));
      #pragma unroll
      for (int i = 0; i < 2; i++){
        acc[i][j] = __builtin_amdgcn_mfma_f32_16x16x32_bf16(ah[i],  bh, acc[i][j], 0, 0, 0);
        acc[i][j] = __builtin_amdgcn_mfma_f32_16x16x32_bf16(ah[i],  bl, acc[i][j], 0, 0, 0);
        acc[i][j] = __builtin_amdgcn_mfma_f32_16x16x32_bf16(al_[i], bh, acc[i][j], 0, 0, 0);
      }
    }
    __syncthreads();
  }
  #pragma unroll
  for (int j = 0; j < 4; j++){
    int col = j * 16 + m15;
    float bv = sg.bias[col];
    #pragma unroll
    for (int i = 0; i < 2; i++){
      #pragma unroll
      for (int r = 0; r < 4; r++){
        int row = r0 + w * 32 + i * 16 + q * 4 + r;
        if (row < N){
          float vv = acc[i][j][r] + bv;
          sg.C[(size_t)row * 64 + col] = vv;
        }
      }
    }
  }
}

// ---------------- fused GAT-aggregate + MFMA GEMM (layer step) ----------------
// Per block: 64 dst rows of one node type. Per K-slot (relation):
//   aggregate phase: 16 groups x 16 lanes run the proven edge loop, now as a
//     2-edge-wide, one-pair-ahead software pipeline (4 edges in flight/group)
//     to compensate the 4-waves/SIMD occupancy with ILP. Per-edge math and
//     per-column accumulation order unchanged (masked tail adds exactly +0.0)
//     -> bitwise-identical output. Split bf16 written directly to LDS.
//   MFMA phase: 4 K-chunks; B staged per chunk; global chunk order identical
//     to the unfused version -> bitwise-identical C.
// LDS: A 16+16 KB, B 4+4 KB = 40 KB -> 4 blocks/CU.

struct GGSeg {
  const unsigned short* BH;
  const unsigned short* BL;
  const float* bias;
  float* C;
  int N; int K; int blk0; int ty;
};
struct GGArgs {
  GGSeg s[3];
  const float* h[3];       // cur h per node type (post, user, ent)
  const float* als;
  const float* ald;
  const int* rowstart;
  const int* csr;
};

__global__ __launch_bounds__(256) void k_gatgemm(GGArgs G){
  __shared__ __align__(16) unsigned short sAh[4 * 64 * 32];
  __shared__ __align__(16) unsigned short sAl[4 * 64 * 32];
  __shared__ __align__(16) unsigned short sBh[64 * 32];
  __shared__ __align__(16) unsigned short sBl[64 * 32];
  int b = blockIdx.x;
  GGSeg sg = G.s[0];
  if (b >= G.s[1].blk0) sg = G.s[1];
  if (b >= G.s[2].blk0) sg = G.s[2];
  const int N = sg.N, K = sg.K, ty = sg.ty;
  int t = threadIdx.x;
  int w = t >> 6, lane = t & 63;
  int q = lane >> 4, m15 = lane & 15;
  int gid = t >> 4, lg = t & 15;        // 16 groups x 16 lanes
  int r0 = (b - sg.blk0) * 64;
  f32x4 acc[4];
  #pragma unroll
  for (int j = 0; j < 4; j++) acc[j] = (f32x4){0.f, 0.f, 0.f, 0.f};

  int brow = t >> 2, bkb = (t & 3) * 8;
  int nslots = K >> 7;
  const int relT[3][3]    = {{0,1,5},{3,4,0},{2,0,0}};
  const int stT[3][3]     = {{1,1,0},{1,1,0},{0,0,0}};
  const int alsoffT[3][3] = {{0,50000,300000},{200000,250000,0},{100000,0,0}};
  const int dgoT[6] = {0,100000,200000,220000,270000,320000};

  for (int s = 0; s < nslots; s++){
    int rel = relT[ty][s];
    const float* __restrict__ h = G.h[stT[ty][s]];
    const float* __restrict__ als = G.als + (size_t)alsoffT[ty][s] * 2;
    int dgo = dgoT[rel];
    // ---- aggregate 64 rows into LDS chunk buffers ----
    #pragma unroll
    for (int pass = 0; pass < 4; pass++){
      int rloc = pass * 16 + gid;
      int row = r0 + rloc;
      float4 a0v = {0.f,0.f,0.f,0.f}, a1v = {0.f,0.f,0.f,0.f};
      float s0 = 0.f, s1 = 0.f;
      if (row < N){
        int gw = dgo + row;
        float2 ad = *(const float2*)(G.ald + (size_t)gw * 2);
        int rs = G.rowstart[gw];
        int re = G.rowstart[gw + 1];
        if (re > rs){
          // 2-edge pair, one-pair-ahead pipeline (4 edges in flight)
          int i0 = G.csr[rs];
          int i1 = (rs + 1 < re) ? G.csr[rs + 1] : i0;
          float2 b0 = *(const float2*)(als + (size_t)i0 * 2);
          float2 b1 = *(const float2*)(als + (size_t)i1 * 2);
          float4 H0 = *(const float4*)(h + (size_t)i0 * 64 + lg * 4);
          float4 H1 = *(const float4*)(h + (size_t)i1 * 64 + lg * 4);
          float msk1 = (rs + 1 < re) ? 1.f : 0.f;
          for (int e = rs; e < re; e += 2){
            int en = e + 2;
            // prefetch next pair (clamped to valid addresses)
            int ni0 = (en < re) ? G.csr[en] : i0;
            int ni1 = (en + 1 < re) ? G.csr[en + 1] : i0;
            float2 nb0 = *(const float2*)(als + (size_t)ni0 * 2);
            float2 nb1 = *(const float2*)(als + (size_t)ni1 * 2);
            float4 nH0 = *(const float4*)(h + (size_t)ni0 * 64 + lg * 4);
            float4 nH1 = *(const float4*)(h + (size_t)ni1 * 64 + lg * 4);
            float nmsk1 = (en + 1 < re) ? 1.f : 0.f;
            // edge e
            float e0 = b0.x + ad.x, e1 = b0.y + ad.y;
            e0 = e0 > 0.f ? e0 : 0.2f * e0;
            e1 = e1 > 0.f ? e1 : 0.2f * e1;
            float p0 = __expf(e0), p1 = __expf(e1);
            a0v.x = fmaf(p0, H0.x, a0v.x); a0v.y = fmaf(p0, H0.y, a0v.y);
            a0v.z = fmaf(p0, H0.z, a0v.z); a0v.w = fmaf(p0, H0.w, a0v.w);
            a1v.x = fmaf(p1, H0.x, a1v.x); a1v.y = fmaf(p1, H0.y, a1v.y);
            a1v.z = fmaf(p1, H0.z, a1v.z); a1v.w = fmaf(p1, H0.w, a1v.w);
            s0 += p0; s1 += p1;
            // edge e+1 (masked tail contributes exactly 0)
            float f0 = b1.x + ad.x, f1 = b1.y + ad.y;
            f0 = f0 > 0.f ? f0 : 0.2f * f0;
            f1 = f1 > 0.f ? f1 : 0.2f * f1;
            float q0 = __expf(f0) * msk1, q1 = __expf(f1) * msk1;
            a0v.x = fmaf(q0, H1.x, a0v.x); a0v.y = fmaf(q0, H1.y, a0v.y);
            a0v.z = fmaf(q0, H1.z, a0v.z); a0v.w = fmaf(q0, H1.w, a0v.w);
            a1v.x = fmaf(q1, H1.x, a1v.x); a1v.y = fmaf(q1, H1.y, a1v.y);
            a1v.z = fmaf(q1, H1.z, a1v.z); a1v.w = fmaf(q1, H1.w, a1v.w);
            s0 += q0; s1 += q1;
            // rotate
            i0 = ni0; i1 = ni1; b0 = nb0; b1 = nb1; H0 = nH0; H1 = nH1; msk1 = nmsk1;
          }
        }
      }
      float rc0 = s0 > 0.f ? 0.5f / s0 : 0.f;
      float rc1 = s1 > 0.f ? 0.5f / s1 : 0.f;
      float v0x = a0v.x*rc0, v0y = a0v.y*rc0, v0z = a0v.z*rc0, v0w = a0v.w*rc0;
      float v1x = a1v.x*rc1, v1y = a1v.y*rc1, v1z = a1v.z*rc1, v1w = a1v.w*rc1;
      ushort4v h0v, h1v, l0v, l1v;
      h0v[0]=f2bf(v0x); h0v[1]=f2bf(v0y); h0v[2]=f2bf(v0z); h0v[3]=f2bf(v0w);
      h1v[0]=f2bf(v1x); h1v[1]=f2bf(v1y); h1v[2]=f2bf(v1z); h1v[3]=f2bf(v1w);
      l0v[0]=f2bf(v0x-bf2f(h0v[0])); l0v[1]=f2bf(v0y-bf2f(h0v[1]));
      l0v[2]=f2bf(v0z-bf2f(h0v[2])); l0v[3]=f2bf(v0w-bf2f(h0v[3]));
      l1v[0]=f2bf(v1x-bf2f(h1v[0])); l1v[1]=f2bf(v1y-bf2f(h1v[1]));
      l1v[2]=f2bf(v1z-bf2f(h1v[2])); l1v[3]=f2bf(v1w-bf2f(h1v[3]));
      int c0 = lg >> 3;               // (lg*4)>>5
      int kk = (lg * 4) & 31;
      *(ushort4v*)(sAh + c0*2048       + swz(rloc, kk)) = h0v;
      *(ushort4v*)(sAh + (2+c0)*2048   + swz(rloc, kk)) = h1v;
      *(ushort4v*)(sAl + c0*2048       + swz(rloc, kk)) = l0v;
      *(ushort4v*)(sAl + (2+c0)*2048   + swz(rloc, kk)) = l1v;
    }
    __syncthreads();
    // ---- 4 K-chunks of MFMA over this slot ----
    for (int c = 0; c < 4; c++){
      int gk = s * 128 + c * 32;
      *(short8*)(sBh + swz(brow, bkb)) = *(const short8*)(sg.BH + (size_t)brow * K + gk + bkb);
      *(short8*)(sBl + swz(brow, bkb)) = *(const short8*)(sg.BL + (size_t)brow * K + gk + bkb);
      __syncthreads();
      int mrow = w * 16 + m15;
      short8 ah  = *(const short8*)(sAh + c*2048 + swz(mrow, q * 8));
      short8 al_ = *(const short8*)(sAl + c*2048 + swz(mrow, q * 8));
      #pragma unroll
      for (int j = 0; j < 4; j++){
        int bn = j * 16 + m15;
        short8 bh = *(const short8*)(sBh + swz(bn, q * 8));
        short8 bl = *(const short8*)(sBl + swz(bn, q * 8));
        acc[j] = __builtin_amdgcn_mfma_f32_16x16x32_bf16(ah,  bh, acc[j], 0, 0, 0);
        acc[j] = __builtin_amdgcn_mfma_f32_16x16x32_bf16(ah,  bl, acc[j], 0, 0, 0);
        acc[j] = __builtin_amdgcn_mfma_f32_16x16x32_bf16(al_, bh, acc[j], 0, 0, 0);
      }
      __syncthreads();
    }
  }
  // ---- epilogue: bias + relu + store ----
  #pragma unroll
  for (int j = 0; j < 4; j++){
    int col = j * 16 + m15;
    float bv = sg.bias[col];
    #pragma unroll
    for (int r = 0; r < 4; r++){
      int row = r0 + w * 16 + q * 4 + r;
      if (row < N){
        float vv = acc[j][r] + bv;
        vv = vv > 0.f ? vv : 0.f;
        sg.C[(size_t)row * 64 + col] = vv;
      }
    }
  }
}

// ---------------- classifier head ----------------

__global__ __launch_bounds__(256) void k_classifier(const float* __restrict__ hpost,
                                                    const float* __restrict__ w1,
                                                    const float* __restrict__ b1,
                                                    const float* __restrict__ w2,
                                                    const float* __restrict__ b2,
                                                    float* __restrict__ out, int N){
  __shared__ float w1s[32 * 64];
  __shared__ float b1s[32];
  __shared__ float w2s[32];
  for (int i = threadIdx.x; i < 2048; i += 256) w1s[i] = w1[i];
  if (threadIdx.x < 32){
    b1s[threadIdx.x] = b1[threadIdx.x];
    w2s[threadIdx.x] = w2[threadIdx.x];
  }
  __syncthreads();
  float bias2 = b2[0];
  for (int n = blockIdx.x * blockDim.x + threadIdx.x; n < N; n += gridDim.x * blockDim.x){
    float4 hr[16];
    const float4* hp = (const float4*)(hpost + (size_t)n * 64);
    #pragma unroll
    for (int q = 0; q < 16; q++) hr[q] = hp[q];
    float o = bias2;
    #pragma unroll 4
    for (int j = 0; j < 32; j++){
      float dacc = b1s[j];
      const float4* wr = (const float4*)(w1s + j * 64);
      #pragma unroll
      for (int q = 0; q < 16; q++){
        float4 w = wr[q]; float4 v = hr[q];
        dacc += w.x*v.x + w.y*v.y + w.z*v.z + w.w*v.w;
      }
      dacc = dacc > 0.f ? dacc : 0.f;
      o += w2s[j] * dacc;
    }
    out[n] = o;
  }
}

// ---------------- host ----------------

static inline size_t align256(size_t x){ return (x + 255) & ~(size_t)255; }

extern "C" void kernel_launch(void* const* d_in, const int* in_sizes, int n_in,
                              void* d_out, int out_size, void* d_ws, size_t ws_size,
                              hipStream_t stream){
  (void)in_sizes; (void)n_in; (void)out_size; (void)ws_size;
  const float* x_post = (const float*)d_in[0];
  const float* x_user = (const float*)d_in[1];
  const float* x_ent  = (const float*)d_in[2];
  EdgeMeta em;
  for (int r = 0; r < 6; r++){
    em.src[r] = (const int*)d_in[3 + 2*r];
    em.dst[r] = (const int*)d_in[4 + 2*r];
  }
  const int Earr[6] = {100000, 200000, 200000, 400000, 400000, 250000};
  const int dgo[6]  = {0, 100000, 200000, 220000, 270000, 320000};
  for (int r = 0; r < 6; r++){ em.E[r] = Earr[r]; em.degoff[r] = dgo[r]; }

  const float* Wp   = (const float*)d_in[15]; const float* bp = (const float*)d_in[16];
  const float* Wu   = (const float*)d_in[17]; const float* bu = (const float*)d_in[18];
  const float* We   = (const float*)d_in[19]; const float* be = (const float*)d_in[20];
  const float* Wsrc = (const float*)d_in[21];
  const float* Wdst = (const float*)d_in[22];
  const float* asrc = (const float*)d_in[23];
  const float* adst = (const float*)d_in[24];
  const float* gatb = (const float*)d_in[25];
  const float* cw1  = (const float*)d_in[26]; const float* cb1 = (const float*)d_in[27];
  const float* cw2  = (const float*)d_in[28]; const float* cb2 = (const float*)d_in[29];
  float* out = (float*)d_out;

  const int NN[3] = {NPOST, NUSER, NENT};

  // ---- workspace ----
  char* p = (char*)d_ws;
  auto alloc = [&](size_t bytes){ char* r = p; p += align256(bytes); return r; };
  float* hA[3]; float* hB[3];
  for (int i = 0; i < 3; i++) hA[i] = (float*)alloc((size_t)NN[i] * 64 * 4);
  for (int i = 0; i < 3; i++) hB[i] = (float*)alloc((size_t)NN[i] * 64 * 4);
  float* als_all = (float*)alloc((size_t)400000 * 2 * 4);
  float* ald_all = (float*)alloc((size_t)NDTOT * 2 * 4);
  float* weff_s = (float*)alloc(1536 * 4);
  float* weff_d = (float*)alloc(1536 * 4);
  unsigned short* WpH = (unsigned short*)alloc(768 * 64 * 2);
  unsigned short* WpL = (unsigned short*)alloc(768 * 64 * 2);
  unsigned short* WuH = (unsigned short*)alloc(32 * 64 * 2);
  unsigned short* WuL = (unsigned short*)alloc(32 * 64 * 2);
  unsigned short* WeH = (unsigned short*)alloc(64 * 64 * 2);
  unsigned short* WeL = (unsigned short*)alloc(64 * 64 * 2);
  unsigned short* lbH = (unsigned short*)alloc(98304 * 2);
  unsigned short* lbL = (unsigned short*)alloc(98304 * 2);
  float* bsum   = (float*)alloc(6 * 64 * 4);
  int* deg      = (int*)alloc((size_t)NDTOT * 4);
  int* rowstart = (int*)alloc((size_t)(NDTOT + 1) * 4);
  int* cursor   = (int*)alloc((size_t)NDTOT * 4);
  int* csr_src  = (int*)alloc((size_t)ETOT * 4);
  int* blocksum = (int*)alloc((size_t)NSCANBLK * 4);

  // ---- CSR build (layer-invariant) ----
  hipMemsetAsync(deg, 0, (size_t)NDTOT * 4, stream);
  k_hist<<<dim3(1563, 6), 256, 0, stream>>>(em, deg);
  k_scanA<<<NSCANBLK, 256, 0, stream>>>(deg, rowstart, blocksum);
  k_scanB<<<1, 256, 0, stream>>>(blocksum);
  k_scanC<<<(NDTOT + 255) / 256, 256, 0, stream>>>(rowstart, blocksum, cursor);
  k_scatter<<<dim3(1563, 6), 256, 0, stream>>>(em, cursor, csr_src);

  // ---- weight prep (single fused launch) ----
  k_prep<<<614, 256, 0, stream>>>(Wp, Wu, We, Wsrc, Wdst, asrc, adst, gatb,
                                  WpH, WpL, WuH, WuL, WeH, WeL, lbH, lbL,
                                  weff_s, weff_d, bsum);

  // ---- input projections (one fused MFMA launch, 3 segments, BM=128) ----
  const int PBLK1 = (NPOST + 127) / 128, PBLK2 = PBLK1 + (NUSER + 127) / 128;
  const int PBLKT = PBLK2 + (NENT + 127) / 128;
  {
    GArgs gp;
    gp.s[0] = { x_post, WpH, WpL, bp, hA[0], NPOST, 768, 0 };
    gp.s[1] = { x_user, WuH, WuL, bu, hA[1], NUSER,  32, PBLK1 };
    gp.s[2] = { x_ent,  WeH, WeL, be, hA[2], NENT,   64, PBLK2 };
    k_mfgemm3<<<PBLKT, 256, 0, stream>>>(gp);
  }

  const int segoff[6] = {0, 24576, 40960, 49152, 73728, 90112};  // (l,type) B offsets

  float* cur[3] = {hA[0], hA[1], hA[2]};
  float* nxt[3] = {hB[0], hB[1], hB[2]};

  // fused layer GEMM grid (BM=64)
  const int GBLK1 = (NPOST + 63) / 64, GBLK2 = GBLK1 + (NUSER + 63) / 64;
  const int GBLKT = GBLK2 + (NENT + 63) / 64;

  for (int l = 0; l < 2; l++){
    k_al_all<<<(820000 + 255) / 256, 256, 0, stream>>>(cur[0], cur[1], cur[2],
                                                       weff_s, weff_d, als_all, ald_all, l);
    {
      GGArgs gg;
      gg.s[0] = { lbH + segoff[l*3+0], lbL + segoff[l*3+0], bsum + (l*3+0)*64,
                  nxt[0], NPOST, 384, 0, 0 };
      gg.s[1] = { lbH + segoff[l*3+1], lbL + segoff[l*3+1], bsum + (l*3+1)*64,
                  nxt[1], NUSER, 256, GBLK1, 1 };
      gg.s[2] = { lbH + segoff[l*3+2], lbL + segoff[l*3+2], bsum + (l*3+2)*64,
                  nxt[2], NENT, 128, GBLK2, 2 };
      gg.h[0] = cur[0]; gg.h[1] = cur[1]; gg.h[2] = cur[2];
      gg.als = als_all; gg.ald = ald_all;
      gg.rowstart = rowstart; gg.csr = csr_src;
      k_gatgemm<<<GBLKT, 256, 0, stream>>>(gg);
    }
    for (int i = 0; i < 3; i++){ float* tmp = cur[i]; cur[i] = nxt[i]; nxt[i] = tmp; }
  }

  k_classifier<<<(NPOST + 255) / 256, 256, 0, stream>>>(cur[0], cw1, cb1, cw2, cb2, out, NPOST);
}